// Round 1
// baseline (8188.033 us; speedup 1.0000x reference)
//
#include <hip/hip_runtime.h>
#include <cstddef>

// WordEncoder: emb gather -> masked LSTM (T=1024 sequential) -> relu(h@Wd+bd)
// Persistent kernel: 256 blocks = 8 batch-groups x 32 unit-groups, 1 block/CU.
// Weights register-resident; h exchanged via agent-scope (IC-coherent) atomics;
// per-batch-group counter sync (32 blocks/group, no grid-wide barrier).

constexpr int NBATCH = 128;
constexpr int TLEN   = 1024;
constexpr int EDIM   = 128;
constexpr int UDIM   = 256;
constexpr int DDIM   = 256;

constexpr int NBG = 8;     // batch groups
constexpr int NUG = 32;    // unit groups
constexpr int BPB = 16;    // batches per block
constexpr int UPB = 8;     // units per block
constexpr int ZC  = 32;    // z cols per block (4 gates x 8 units)
constexpr int YC  = 8;     // y cols per block
constexpr int NC  = 40;    // total cols
constexpr int KSL = 12;    // k slices (k-split)
constexpr int KT  = 32;    // k per slice (12*32 = 384 = U + E)
constexpr int HXROW = 432; // (384/32)*36 padded row (+4 f32 per 32 -> bank spread)
constexpr int REDROW = NC * BPB + 8; // 648

__device__ float        g_h[2][NBATCH][UDIM];
__device__ unsigned int g_cnt[NBG];

__device__ __forceinline__ int pidx(int k) { return ((k >> 5) * 36) + (k & 31); }

__global__ void we_init() {
  int i = blockIdx.x * 256 + threadIdx.x;
  float* p = &g_h[0][0][0];
  if (i < 2 * NBATCH * UDIM)
    __hip_atomic_store(&p[i], 0.f, __ATOMIC_RELAXED, __HIP_MEMORY_SCOPE_AGENT);
  if (i < NBG)
    __hip_atomic_store(&g_cnt[i], 0u, __ATOMIC_RELAXED, __HIP_MEMORY_SCOPE_AGENT);
}

__global__ __launch_bounds__(256, 1) void we_lstm(
    const int* __restrict__ tokens, const float* __restrict__ emb,
    const float* __restrict__ Wk, const float* __restrict__ Wr,
    const float* __restrict__ bz, const float* __restrict__ Wd,
    const float* __restrict__ bd, float* __restrict__ out)
{
  __shared__ float hx[BPB][HXROW];     // staged [h(256) | x(128)] per batch, padded
  __shared__ float red[KSL][REDROW];   // k-split partials
  __shared__ float zs[BPB * ZC];       // reduced z (pre-bias)
  __shared__ float bias_s[ZC];
  __shared__ float bd_s[YC];
  __shared__ int   tok_s[BPB];

  const int tid = threadIdx.x;
  const int bid = blockIdx.x;
  const int bg  = bid & (NBG - 1);   // bid%8: sync-group stays on one XCD (heuristic only)
  const int ug  = bid >> 3;
  const int b0  = bg * BPB;
  const int u0  = ug * UPB;
  const int d0  = ug * YC;

  // GEMM thread decomposition: 240 active = 2 batch-halves x 10 col-quads x 12 k-slices
  const bool act = tid < 240;
  const int bh  = tid / 120;
  const int rr  = tid % 120;
  const int cq  = rr / 12;
  const int ksl = rr % 12;

  // ---- prologue: load this thread's weight slice into registers (32k x 4c) ----
  float w[KT * 4];
  if (act) {
#pragma unroll
    for (int kk = 0; kk < KT; ++kk) {
      const int k = ksl * KT + kk;
#pragma unroll
      for (int cc = 0; cc < 4; ++cc) {
        const int c = cq * 4 + cc;
        float wv;
        if (c < ZC) { // z column: gate p = c>>3, unit u0 + (c&7)
          const int j = ((c >> 3) << 8) + u0 + (c & 7);
          wv = (k < UDIM) ? Wr[k * 1024 + j] : Wk[(k - UDIM) * 1024 + j];
        } else {      // y column: Wd on h-part only
          wv = (k < UDIM) ? Wd[k * DDIM + d0 + (c - ZC)] : 0.f;
        }
        w[kk * 4 + cc] = wv;
      }
    }
  }
  if (tid < ZC) {
    bias_s[tid] = bz[((tid >> 3) << 8) + u0 + (tid & 7)];
  } else if (tid < ZC + YC) {
    bd_s[tid - ZC] = bd[d0 + tid - ZC];
  }
  float creg = 0.f;            // c-state for (gb,gu), gate threads tid<128
  const int gb = tid >> 3;
  const int gu = tid & 7;

  for (int it = 0; it <= TLEN; ++it) {
    const int rp = it & 1;     // read parity: g_h[rp] == h_{it-1}
    if (tid < BPB)
      tok_s[tid] = (it < TLEN) ? tokens[(b0 + tid) * TLEN + it] : 0;
    // stage h_{it-1}: 16 rows x 256, coherent scalar loads (bypass stale L1/L2)
#pragma unroll
    for (int r = 0; r < 16; ++r) {
      float v = __hip_atomic_load(&g_h[rp][b0 + r][tid], __ATOMIC_RELAXED,
                                  __HIP_MEMORY_SCOPE_AGENT);
      hx[r][pidx(tid)] = v;
    }
    __syncthreads();
    // stage x_it = emb[tok]: 16 rows x 128 (plain cached loads, read-only data)
#pragma unroll
    for (int r = 0; r < 2; ++r) {
      const int ch = tid + r * 256;
      const int b  = ch >> 5;
      const int e  = (ch & 31) << 2;
      float4 v = make_float4(0.f, 0.f, 0.f, 0.f);
      if (it < TLEN) {
        const int tk = tok_s[b];
        v = *(const float4*)&emb[(size_t)tk * EDIM + e];
      }
      *(float4*)&hx[b][pidx(UDIM + e)] = v;
    }
    __syncthreads();
    // ---- register-tiled GEMM: acc[8b][4c] over this thread's 32-k slice ----
    if (act) {
      float acc[8][4];
#pragma unroll
      for (int b2 = 0; b2 < 8; ++b2)
#pragma unroll
        for (int cc = 0; cc < 4; ++cc) acc[b2][cc] = 0.f;
#pragma unroll
      for (int k4 = 0; k4 < KT / 4; ++k4) {
        const int hoff = pidx(ksl * KT + k4 * 4);
        float4 hv[8];
#pragma unroll
        for (int b2 = 0; b2 < 8; ++b2)
          hv[b2] = *(const float4*)&hx[bh * 8 + b2][hoff];
#pragma unroll
        for (int j = 0; j < 4; ++j) {
#pragma unroll
          for (int b2 = 0; b2 < 8; ++b2) {
            const float hval = (j == 0) ? hv[b2].x : (j == 1) ? hv[b2].y
                               : (j == 2) ? hv[b2].z : hv[b2].w;
#pragma unroll
            for (int cc = 0; cc < 4; ++cc)
              acc[b2][cc] += hval * w[(k4 * 4 + j) * 4 + cc];
          }
        }
      }
#pragma unroll
      for (int b2 = 0; b2 < 8; ++b2) {
        const int ob = (bh * 8 + b2) * NC + cq * 4;
        *(float4*)&red[ksl][ob] = *(const float4*)&acc[b2][0];
      }
    }
    __syncthreads();
    // ---- k-reduce; z -> LDS, y -> relu -> global (for step it-1) ----
#pragma unroll
    for (int r = 0; r < 3; ++r) {
      const int o = tid + r * 256;
      if (o < BPB * NC) {
        float s = 0.f;
#pragma unroll
        for (int q = 0; q < KSL; ++q) s += red[q][o];
        const int b2 = o / NC;
        const int c  = o - b2 * NC;
        if (c < ZC) {
          zs[b2 * ZC + c] = s;
        } else if (it > 0) {
          const float yv = s + bd_s[c - ZC];
          out[((size_t)(b0 + b2) * TLEN + (it - 1)) * DDIM + d0 + (c - ZC)] =
              fmaxf(yv, 0.f);
        }
      }
    }
    __syncthreads();
    if (it < TLEN) {
      // ---- gates: tid<128 owns (batch gb, unit u0+gu) ----
      if (tid < BPB * UPB) {
        const float zi = zs[gb * ZC + gu]      + bias_s[gu];
        const float zf = zs[gb * ZC + 8 + gu]  + bias_s[8 + gu];
        const float zg = zs[gb * ZC + 16 + gu] + bias_s[16 + gu];
        const float zo = zs[gb * ZC + 24 + gu] + bias_s[24 + gu];
        const float gi = 1.f / (1.f + __expf(-zi));
        const float gf = 1.f / (1.f + __expf(-zf));
        const float gg = 1.f - 2.f / (1.f + __expf(2.f * zg)); // tanh
        const float go = 1.f / (1.f + __expf(-zo));
        const float cn = gf * creg + gi * gg;
        const float th = 1.f - 2.f / (1.f + __expf(2.f * cn));
        const float hn = go * th;
        const bool msk = (tok_s[gb] != 0);
        const float hold = hx[gb][pidx(u0 + gu)];
        const float h2 = msk ? hn : hold;
        creg = msk ? cn : creg;
        __hip_atomic_store(&g_h[1 - rp][b0 + gb][u0 + gu], h2,
                           __ATOMIC_RELAXED, __HIP_MEMORY_SCOPE_AGENT);
      }
      __syncthreads(); // drains stores (vmcnt) before the counter bump
      // ---- batch-group sync: 32 blocks, monotonic counter at coherent point ----
      if (tid == 0) {
        __hip_atomic_fetch_add(&g_cnt[bg], 1u, __ATOMIC_RELAXED,
                               __HIP_MEMORY_SCOPE_AGENT);
        const unsigned tgt = (unsigned)(NUG * (it + 1));
        while (__hip_atomic_load(&g_cnt[bg], __ATOMIC_RELAXED,
                                 __HIP_MEMORY_SCOPE_AGENT) < tgt)
          __builtin_amdgcn_s_sleep(2);
      }
      __syncthreads();
    }
  }
}

extern "C" void kernel_launch(void* const* d_in, const int* in_sizes, int n_in,
                              void* d_out, int out_size, void* d_ws, size_t ws_size,
                              hipStream_t stream) {
  const int*   tokens = (const int*)d_in[0];
  const float* emb    = (const float*)d_in[1];
  const float* Wk     = (const float*)d_in[2];
  const float* Wr     = (const float*)d_in[3];
  const float* bz     = (const float*)d_in[4];
  const float* Wd     = (const float*)d_in[5];
  const float* bd     = (const float*)d_in[6];
  float* out = (float*)d_out;
  (void)in_sizes; (void)n_in; (void)out_size; (void)d_ws; (void)ws_size;
  hipLaunchKernelGGL(we_init, dim3(256), dim3(256), 0, stream);
  hipLaunchKernelGGL(we_lstm, dim3(256), dim3(256), 0, stream,
                     tokens, emb, Wk, Wr, bz, Wd, bd, out);
}

// Round 2
// 5889.931 us; speedup vs baseline: 1.3902x; 1.3902x over previous
//
#include <hip/hip_runtime.h>
#include <cstddef>

// WordEncoder: emb gather -> masked LSTM (T=1024) -> relu(h@Wd+bd)
// Recurrent kernel: 256 blocks = 8 batch-groups x 32 unit-groups, 1/CU.
// h exchanged via self-validating (tag|value) u64 packets at agent scope
// (single IC round-trip, parity double-buffered). y projection moved to a
// separate parallel kernel reading the h history streamed into d_out.

constexpr int TLEN = 1024;
constexpr int EDIM = 128;
constexpr int UDIM = 256;
constexpr int DDIM = 256;

constexpr int NBG = 8;     // batch groups
constexpr int BPB = 16;    // batches per block
constexpr int UPB = 8;     // units per block
constexpr int ZC  = 32;    // z cols per block (4 gates x 8 units)
constexpr int KSL = 16;    // k slices
constexpr int KT  = 24;    // k per slice (16*24 = 384 = U + E)
constexpr int HXROW = 432; // (384/32)*36 padded row
constexpr int REDROW = 516; // 512 + 4 (bank balance, 16B-aligned)

__device__ unsigned long long g_pkt[2][128][256]; // [parity][batch][unit] = tag|h

__device__ __forceinline__ int pidx(int k) { return ((k >> 5) * 36) + (k & 31); }

__global__ void we_init() {
  const int i = blockIdx.x * 256 + threadIdx.x;
  unsigned long long* p = &g_pkt[0][0][0];
  __hip_atomic_store(&p[i], 0xFFFFFFFF00000000ull, __ATOMIC_RELAXED,
                     __HIP_MEMORY_SCOPE_AGENT);
}

__global__ __launch_bounds__(256, 1) void we_lstm(
    const int* __restrict__ tokens, const float* __restrict__ emb,
    const float* __restrict__ Wk, const float* __restrict__ Wr,
    const float* __restrict__ bz, float* __restrict__ out)
{
  __shared__ float hx[BPB][HXROW];     // [h(256) | x(128)] per batch, padded
  __shared__ float red[KSL][REDROW];   // k-split partials
  __shared__ float zs[BPB * 36];       // reduced z (pre-bias), padded stride
  __shared__ float bias_s[ZC];
  __shared__ int   tok_s[2][BPB];      // parity double-buffered

  const int tid = threadIdx.x;
  const int bid = blockIdx.x;
  const int bg  = bid & (NBG - 1);
  const int ug  = bid >> 3;
  const int b0  = bg * BPB;
  const int u0  = ug * UPB;

  // GEMM decomposition: 256 = 2 batch-halves x 8 col-quads x 16 k-slices
  const int ksl = tid & 15;
  const int cq  = (tid >> 4) & 7;
  const int bh  = tid >> 7;

  // ---- prologue: weight slice into registers (24k x 4c per thread) ----
  float w[KT * 4];
#pragma unroll
  for (int kk = 0; kk < KT; ++kk) {
    const int k = ksl * KT + kk;
#pragma unroll
    for (int cc = 0; cc < 4; ++cc) {
      const int c = cq * 4 + cc;
      const int j = ((c >> 3) << 8) + u0 + (c & 7);
      const float* src = (k < UDIM) ? &Wr[k * 1024 + j]
                                    : &Wk[(k - UDIM) * 1024 + j];
      w[kk * 4 + cc] = *src;
    }
  }
  if (tid < ZC) bias_s[tid] = bz[((tid >> 3) << 8) + u0 + (tid & 7)];

  float creg = 0.f;
  const int gb = tid >> 3;   // gate thread batch (tid<128)
  const int gu = tid & 7;    // gate thread unit

  const int xb0 = tid >> 5;            // x-stage: batch 0..7 (+8 second pass)
  const int xe  = (tid & 31) << 2;     // x-stage: 4-elem column

  for (int it = 0; it < TLEN; ++it) {
    const int cur = it & 1;
    if (tid < BPB) tok_s[cur][tid] = tokens[(b0 + tid) * TLEN + it];
    __syncthreads();

    // issue x loads (L2/L3) then packet prefetch (IC) -- all in flight together
    const float4 xv0 = *(const float4*)&emb[(size_t)tok_s[cur][xb0] * EDIM + xe];
    const float4 xv1 = *(const float4*)&emb[(size_t)tok_s[cur][xb0 + 8] * EDIM + xe];

    unsigned long long pv[16];
    const unsigned want = (unsigned)(it - 1);
    const int rp = (it - 1) & 1;
    if (it > 0) {
#pragma unroll
      for (int j = 0; j < 16; ++j)
        pv[j] = __hip_atomic_load(&g_pkt[rp][b0 + j][tid], __ATOMIC_RELAXED,
                                  __HIP_MEMORY_SCOPE_AGENT);
    }
    *(float4*)&hx[xb0][pidx(UDIM + xe)]     = xv0;
    *(float4*)&hx[xb0 + 8][pidx(UDIM + xe)] = xv1;
    if (it > 0) {
#pragma unroll
      for (int j = 0; j < 16; ++j) {
        while ((unsigned)(pv[j] >> 32) != want) {
          __builtin_amdgcn_s_sleep(1);
          pv[j] = __hip_atomic_load(&g_pkt[rp][b0 + j][tid], __ATOMIC_RELAXED,
                                    __HIP_MEMORY_SCOPE_AGENT);
        }
        hx[j][pidx(tid)] = __uint_as_float((unsigned)pv[j]);
      }
    } else {
#pragma unroll
      for (int j = 0; j < 16; ++j) hx[j][pidx(tid)] = 0.f;
    }
    __syncthreads();

    // ---- register-tiled GEMM: acc[8b][4c] over 24-k slice ----
    float acc[8][4];
#pragma unroll
    for (int b2 = 0; b2 < 8; ++b2)
#pragma unroll
      for (int cc = 0; cc < 4; ++cc) acc[b2][cc] = 0.f;
#pragma unroll
    for (int k4 = 0; k4 < KT / 4; ++k4) {
      const int hoff = pidx(ksl * KT + k4 * 4);
      float4 hv[8];
#pragma unroll
      for (int b2 = 0; b2 < 8; ++b2)
        hv[b2] = *(const float4*)&hx[bh * 8 + b2][hoff];
#pragma unroll
      for (int jj = 0; jj < 4; ++jj) {
#pragma unroll
        for (int b2 = 0; b2 < 8; ++b2) {
          const float hval = (jj == 0) ? hv[b2].x : (jj == 1) ? hv[b2].y
                             : (jj == 2) ? hv[b2].z : hv[b2].w;
#pragma unroll
          for (int cc = 0; cc < 4; ++cc)
            acc[b2][cc] += hval * w[(k4 * 4 + jj) * 4 + cc];
        }
      }
    }
#pragma unroll
    for (int b2 = 0; b2 < 8; ++b2)
      *(float4*)&red[ksl][(bh * 8 + b2) * ZC + cq * 4] =
          *(const float4*)&acc[b2][0];
    __syncthreads();

    // ---- k-reduce -> zs (padded stride 36) ----
#pragma unroll
    for (int r = 0; r < 2; ++r) {
      const int n = tid + r * 256;
      float s = 0.f;
#pragma unroll
      for (int q = 0; q < KSL; ++q) s += red[q][n];
      zs[(n >> 5) * 36 + (n & 31)] = s;
    }
    __syncthreads();

    // ---- gates: tid<128 owns (batch gb, unit u0+gu) ----
    if (tid < BPB * UPB) {
      const float zi = zs[gb * 36 + gu]      + bias_s[gu];
      const float zf = zs[gb * 36 + 8 + gu]  + bias_s[8 + gu];
      const float zg = zs[gb * 36 + 16 + gu] + bias_s[16 + gu];
      const float zo = zs[gb * 36 + 24 + gu] + bias_s[24 + gu];
      const float gi = 1.f / (1.f + __expf(-zi));
      const float gf = 1.f / (1.f + __expf(-zf));
      const float gg = 1.f - 2.f / (1.f + __expf(2.f * zg)); // tanh
      const float go = 1.f / (1.f + __expf(-zo));
      const float cn = gf * creg + gi * gg;
      const float th = 1.f - 2.f / (1.f + __expf(2.f * cn));
      const float hn = go * th;
      const bool msk = (tok_s[cur][gb] != 0);
      const float hold = hx[gb][pidx(u0 + gu)];
      const float h2 = msk ? hn : hold;
      creg = msk ? cn : creg;
      const unsigned long long pkt =
          ((unsigned long long)(unsigned)it << 32) | __float_as_uint(h2);
      __hip_atomic_store(&g_pkt[cur][b0 + gb][u0 + gu], pkt, __ATOMIC_RELAXED,
                         __HIP_MEMORY_SCOPE_AGENT);
      __builtin_nontemporal_store(
          h2, &out[((size_t)(b0 + gb) * TLEN + it) * DDIM + u0 + gu]);
    }
    __syncthreads();
  }
}

// y = relu(H @ Wd + bd), in place over d_out (h history -> y). 32 rows/block.
__global__ __launch_bounds__(256, 2) void we_proj(
    const float* __restrict__ Wd, const float* __restrict__ bd,
    float* __restrict__ out)
{
  __shared__ float hs[32][260];
  __shared__ float ws[32][260];
  __shared__ float bds[DDIM];

  const int tid = threadIdx.x;
  const size_t row0 = (size_t)blockIdx.x * 32;

  // stage 32 h rows (float4, coalesced)
#pragma unroll
  for (int j2 = 0; j2 < 8; ++j2) {
    const int idx = tid + j2 * 256;
    const int r = idx >> 6;
    const int cq = idx & 63;
    *(float4*)&hs[r][cq * 4] = *(const float4*)&out[(row0 + r) * DDIM + cq * 4];
  }
  bds[tid] = bd[tid];

  const int rg = tid >> 5;          // rows rg, rg+8, rg+16, rg+24 (bank-spread)
  const int c0 = (tid & 31) * 8;
  float acc[4][8];
#pragma unroll
  for (int i = 0; i < 4; ++i)
#pragma unroll
    for (int c = 0; c < 8; ++c) acc[i][c] = 0.f;

  for (int kt = 0; kt < 8; ++kt) {
    __syncthreads();
#pragma unroll
    for (int j2 = 0; j2 < 8; ++j2) {
      const int idx = tid + j2 * 256;
      const int kk = idx >> 6;
      const int cq = idx & 63;
      *(float4*)&ws[kk][cq * 4] =
          *(const float4*)&Wd[(size_t)(kt * 32 + kk) * DDIM + cq * 4];
    }
    __syncthreads();
#pragma unroll
    for (int kk = 0; kk < 32; ++kk) {
      const float4 wv0 = *(const float4*)&ws[kk][c0];
      const float4 wv1 = *(const float4*)&ws[kk][c0 + 4];
#pragma unroll
      for (int i = 0; i < 4; ++i) {
        const float hval = hs[rg + i * 8][kt * 32 + kk];
        acc[i][0] += hval * wv0.x; acc[i][1] += hval * wv0.y;
        acc[i][2] += hval * wv0.z; acc[i][3] += hval * wv0.w;
        acc[i][4] += hval * wv1.x; acc[i][5] += hval * wv1.y;
        acc[i][6] += hval * wv1.z; acc[i][7] += hval * wv1.w;
      }
    }
  }
#pragma unroll
  for (int i = 0; i < 4; ++i) {
    float4 y0, y1;
    y0.x = fmaxf(acc[i][0] + bds[c0 + 0], 0.f);
    y0.y = fmaxf(acc[i][1] + bds[c0 + 1], 0.f);
    y0.z = fmaxf(acc[i][2] + bds[c0 + 2], 0.f);
    y0.w = fmaxf(acc[i][3] + bds[c0 + 3], 0.f);
    y1.x = fmaxf(acc[i][4] + bds[c0 + 4], 0.f);
    y1.y = fmaxf(acc[i][5] + bds[c0 + 5], 0.f);
    y1.z = fmaxf(acc[i][6] + bds[c0 + 6], 0.f);
    y1.w = fmaxf(acc[i][7] + bds[c0 + 7], 0.f);
    const size_t orow = (row0 + rg + i * 8) * DDIM;
    *(float4*)&out[orow + c0]     = y0;
    *(float4*)&out[orow + c0 + 4] = y1;
  }
}

extern "C" void kernel_launch(void* const* d_in, const int* in_sizes, int n_in,
                              void* d_out, int out_size, void* d_ws, size_t ws_size,
                              hipStream_t stream) {
  const int*   tokens = (const int*)d_in[0];
  const float* emb    = (const float*)d_in[1];
  const float* Wk     = (const float*)d_in[2];
  const float* Wr     = (const float*)d_in[3];
  const float* bz     = (const float*)d_in[4];
  const float* Wd     = (const float*)d_in[5];
  const float* bd     = (const float*)d_in[6];
  float* out = (float*)d_out;
  (void)in_sizes; (void)n_in; (void)out_size; (void)d_ws; (void)ws_size;
  hipLaunchKernelGGL(we_init, dim3(256), dim3(256), 0, stream);
  hipLaunchKernelGGL(we_lstm, dim3(256), dim3(256), 0, stream,
                     tokens, emb, Wk, Wr, bz, out);
  hipLaunchKernelGGL(we_proj, dim3(128 * TLEN / 32), dim3(256), 0, stream,
                     Wd, bd, out);
}

// Round 3
// 5796.053 us; speedup vs baseline: 1.4127x; 1.0162x over previous
//
#include <hip/hip_runtime.h>
#include <cstddef>

// WordEncoder: emb gather -> masked LSTM (T=1024) -> relu(h@Wd+bd)
// Recurrent kernel: 512 blocks = 16 batch-groups x 32 unit-groups, 2/CU so
// one group's IC-latency hides under the other's compute. h exchanged via
// (tag|value) u64 packets at agent scope, parallel re-poll (1 RT per retry).
// In-wave shfl_xor k-reduce (no red LDS), 2 barriers/step.

constexpr int TLEN = 1024;
constexpr int EDIM = 128;
constexpr int UDIM = 256;
constexpr int DDIM = 256;

constexpr int NBG = 16;    // batch groups
constexpr int BPB = 8;     // batches per block
constexpr int UPB = 8;     // units per block
constexpr int ZC  = 32;    // z cols per block (4 gates x 8 units)
constexpr int KSL = 16;    // k slices (reduced via shfl_xor in 16-lane groups)
constexpr int KT  = 24;    // k per slice (16*24 = 384 = U + E)
constexpr int HXROW = 432; // (384/32)*36 padded row

__device__ unsigned long long g_pkt[2][128][256]; // [parity][batch][unit] = tag|h

__device__ __forceinline__ int pidx(int k) { return ((k >> 5) * 36) + (k & 31); }

__global__ void we_init() {
  const int i = blockIdx.x * 256 + threadIdx.x;
  unsigned long long* p = &g_pkt[0][0][0];
  __hip_atomic_store(&p[i], 0xFFFFFFFF00000000ull, __ATOMIC_RELAXED,
                     __HIP_MEMORY_SCOPE_AGENT);
}

__global__ __launch_bounds__(256, 2) void we_lstm(
    const int* __restrict__ tokens, const float* __restrict__ emb,
    const float* __restrict__ Wk, const float* __restrict__ Wr,
    const float* __restrict__ bz, float* __restrict__ out)
{
  __shared__ float hx[2][BPB][HXROW]; // parity-dbuf [h(256)|x(128)], padded
  __shared__ float zs[BPB * 36];      // reduced z (pre-bias), padded stride
  __shared__ float bias_s[ZC];

  const int tid = threadIdx.x;
  const int bid = blockIdx.x;
  const int bg  = bid >> 5;          // contiguous 32-block sync groups
  const int ug  = bid & 31;
  const int b0  = bg * BPB;
  const int u0  = ug * UPB;

  // GEMM decomposition: 256 = 2 batch-halves x 8 col-quads x 16 k-slices
  const int ksl = tid & 15;
  const int cq  = (tid >> 4) & 7;
  const int bh  = tid >> 7;

  // ---- prologue: weight slice into registers (24k x 4c per thread) ----
  float w[KT * 4];
#pragma unroll
  for (int kk = 0; kk < KT; ++kk) {
    const int k = ksl * KT + kk;
#pragma unroll
    for (int cc = 0; cc < 4; ++cc) {
      const int c = cq * 4 + cc;
      const int j = ((c >> 3) << 8) + u0 + (c & 7);
      w[kk * 4 + cc] = (k < UDIM) ? Wr[k * 1024 + j] : Wk[(k - UDIM) * 1024 + j];
    }
  }
  if (tid < ZC) bias_s[tid] = bz[((tid >> 3) << 8) + u0 + (tid & 7)];

  float creg = 0.f;
  const int gb = tid >> 3;        // gate thread batch (tid<64)
  const int gu = tid & 7;         // gate thread unit

  const int xb = tid >> 5;        // x-stage batch 0..7
  const int xe = (tid & 31) << 2; // x-stage 4-elem column

  for (int it = 0; it < TLEN; ++it) {
    const int cur = it & 1;
    float (*hxc)[HXROW] = hx[cur];

    // ---- x stage (direct gather; no barrier needed before use) ----
    const int tok_x = tokens[(b0 + xb) * TLEN + it];
    const float4 xv = *(const float4*)&emb[(size_t)tok_x * EDIM + xe];

    // ---- h exchange: parallel poll, 1 IC round-trip per retry ----
    if (it > 0) {
      const unsigned want = (unsigned)(it - 1);
      const int rp = (it - 1) & 1;
      unsigned long long pv[BPB];
#pragma unroll
      for (int j = 0; j < BPB; ++j)
        pv[j] = __hip_atomic_load(&g_pkt[rp][b0 + j][tid], __ATOMIC_RELAXED,
                                  __HIP_MEMORY_SCOPE_AGENT);
      *(float4*)&hxc[xb][pidx(UDIM + xe)] = xv;
      while (true) {
        bool ok = true;
#pragma unroll
        for (int j = 0; j < BPB; ++j)
          ok &= ((unsigned)(pv[j] >> 32) == want);
        if (ok) break;
        __builtin_amdgcn_s_sleep(1);
#pragma unroll
        for (int j = 0; j < BPB; ++j)
          pv[j] = __hip_atomic_load(&g_pkt[rp][b0 + j][tid], __ATOMIC_RELAXED,
                                    __HIP_MEMORY_SCOPE_AGENT);
      }
#pragma unroll
      for (int j = 0; j < BPB; ++j)
        hxc[j][pidx(tid)] = __uint_as_float((unsigned)pv[j]);
    } else {
      *(float4*)&hxc[xb][pidx(UDIM + xe)] = xv;
#pragma unroll
      for (int j = 0; j < BPB; ++j) hxc[j][pidx(tid)] = 0.f;
    }
    __syncthreads(); // A: hx[cur] fully staged

    // ---- register-tiled GEMM: acc[4 rows][4 cols] over 24-k slice ----
    float acc[4][4];
#pragma unroll
    for (int i = 0; i < 4; ++i)
#pragma unroll
      for (int cc = 0; cc < 4; ++cc) acc[i][cc] = 0.f;
#pragma unroll
    for (int k4 = 0; k4 < KT / 4; ++k4) {
      const int hoff = pidx(ksl * KT + k4 * 4);
      float4 hv[4];
#pragma unroll
      for (int i = 0; i < 4; ++i)
        hv[i] = *(const float4*)&hxc[bh * 4 + i][hoff];
#pragma unroll
      for (int jj = 0; jj < 4; ++jj) {
#pragma unroll
        for (int i = 0; i < 4; ++i) {
          const float hval = (jj == 0) ? hv[i].x : (jj == 1) ? hv[i].y
                             : (jj == 2) ? hv[i].z : hv[i].w;
#pragma unroll
          for (int cc = 0; cc < 4; ++cc)
            acc[i][cc] += hval * w[(k4 * 4 + jj) * 4 + cc];
        }
      }
    }

    // ---- in-wave k-reduce: ksl = 16 contiguous lanes, xor butterfly ----
#pragma unroll
    for (int i = 0; i < 4; ++i)
#pragma unroll
      for (int cc = 0; cc < 4; ++cc) {
        float v = acc[i][cc];
        v += __shfl_xor(v, 1);
        v += __shfl_xor(v, 2);
        v += __shfl_xor(v, 4);
        v += __shfl_xor(v, 8);
        acc[i][cc] = v;
      }
    if (ksl == 0) {
#pragma unroll
      for (int i = 0; i < 4; ++i)
        *(float4*)&zs[(bh * 4 + i) * 36 + cq * 4] =
            make_float4(acc[i][0], acc[i][1], acc[i][2], acc[i][3]);
    }
    __syncthreads(); // B: zs ready

    // ---- gates: tid<64 owns (batch gb, unit u0+gu) ----
    if (tid < BPB * UPB) {
      const float zi = zs[gb * 36 + gu]      + bias_s[gu];
      const float zf = zs[gb * 36 + 8 + gu]  + bias_s[8 + gu];
      const float zg = zs[gb * 36 + 16 + gu] + bias_s[16 + gu];
      const float zo = zs[gb * 36 + 24 + gu] + bias_s[24 + gu];
      const float gi = 1.f / (1.f + __expf(-zi));
      const float gf = 1.f / (1.f + __expf(-zf));
      const float gg = 1.f - 2.f / (1.f + __expf(2.f * zg)); // tanh
      const float go = 1.f / (1.f + __expf(-zo));
      const float cn = gf * creg + gi * gg;
      const float th = 1.f - 2.f / (1.f + __expf(2.f * cn));
      const float hn = go * th;
      const bool msk = (tokens[(b0 + gb) * TLEN + it] != 0);
      const float hold = hxc[gb][pidx(u0 + gu)];
      const float h2 = msk ? hn : hold;
      creg = msk ? cn : creg;
      const unsigned long long pkt =
          ((unsigned long long)(unsigned)it << 32) | __float_as_uint(h2);
      __hip_atomic_store(&g_pkt[cur][b0 + gb][u0 + gu], pkt, __ATOMIC_RELAXED,
                         __HIP_MEMORY_SCOPE_AGENT);
      __builtin_nontemporal_store(
          h2, &out[((size_t)(b0 + gb) * TLEN + it) * DDIM + u0 + gu]);
    }
    // no end barrier: next step's hx[1-cur] writes can't race reads of hx[cur];
    // zs(it+1) writes are ordered after barrier A(it+1); h ordering is packet-
    // self-clocked (non-gate waves spin until this block's gates publish).
  }
}

// y = relu(H @ Wd + bd), in place over d_out (h history -> y). 32 rows/block.
__global__ __launch_bounds__(256, 2) void we_proj(
    const float* __restrict__ Wd, const float* __restrict__ bd,
    float* __restrict__ out)
{
  __shared__ float hs[32][260];
  __shared__ float ws[32][260];
  __shared__ float bds[DDIM];

  const int tid = threadIdx.x;
  const size_t row0 = (size_t)blockIdx.x * 32;

#pragma unroll
  for (int j2 = 0; j2 < 8; ++j2) {
    const int idx = tid + j2 * 256;
    const int r = idx >> 6;
    const int cq = idx & 63;
    *(float4*)&hs[r][cq * 4] = *(const float4*)&out[(row0 + r) * DDIM + cq * 4];
  }
  bds[tid] = bd[tid];

  const int rg = tid >> 5;
  const int c0 = (tid & 31) * 8;
  float acc[4][8];
#pragma unroll
  for (int i = 0; i < 4; ++i)
#pragma unroll
    for (int c = 0; c < 8; ++c) acc[i][c] = 0.f;

  for (int kt = 0; kt < 8; ++kt) {
    __syncthreads();
#pragma unroll
    for (int j2 = 0; j2 < 8; ++j2) {
      const int idx = tid + j2 * 256;
      const int kk = idx >> 6;
      const int cq = idx & 63;
      *(float4*)&ws[kk][cq * 4] =
          *(const float4*)&Wd[(size_t)(kt * 32 + kk) * DDIM + cq * 4];
    }
    __syncthreads();
#pragma unroll
    for (int kk = 0; kk < 32; ++kk) {
      const float4 wv0 = *(const float4*)&ws[kk][c0];
      const float4 wv1 = *(const float4*)&ws[kk][c0 + 4];
#pragma unroll
      for (int i = 0; i < 4; ++i) {
        const float hval = hs[rg + i * 8][kt * 32 + kk];
        acc[i][0] += hval * wv0.x; acc[i][1] += hval * wv0.y;
        acc[i][2] += hval * wv0.z; acc[i][3] += hval * wv0.w;
        acc[i][4] += hval * wv1.x; acc[i][5] += hval * wv1.y;
        acc[i][6] += hval * wv1.z; acc[i][7] += hval * wv1.w;
      }
    }
  }
#pragma unroll
  for (int i = 0; i < 4; ++i) {
    float4 y0, y1;
    y0.x = fmaxf(acc[i][0] + bds[c0 + 0], 0.f);
    y0.y = fmaxf(acc[i][1] + bds[c0 + 1], 0.f);
    y0.z = fmaxf(acc[i][2] + bds[c0 + 2], 0.f);
    y0.w = fmaxf(acc[i][3] + bds[c0 + 3], 0.f);
    y1.x = fmaxf(acc[i][4] + bds[c0 + 4], 0.f);
    y1.y = fmaxf(acc[i][5] + bds[c0 + 5], 0.f);
    y1.z = fmaxf(acc[i][6] + bds[c0 + 6], 0.f);
    y1.w = fmaxf(acc[i][7] + bds[c0 + 7], 0.f);
    const size_t orow = (row0 + rg + i * 8) * DDIM;
    *(float4*)&out[orow + c0]     = y0;
    *(float4*)&out[orow + c0 + 4] = y1;
  }
}

extern "C" void kernel_launch(void* const* d_in, const int* in_sizes, int n_in,
                              void* d_out, int out_size, void* d_ws, size_t ws_size,
                              hipStream_t stream) {
  const int*   tokens = (const int*)d_in[0];
  const float* emb    = (const float*)d_in[1];
  const float* Wk     = (const float*)d_in[2];
  const float* Wr     = (const float*)d_in[3];
  const float* bz     = (const float*)d_in[4];
  const float* Wd     = (const float*)d_in[5];
  const float* bd     = (const float*)d_in[6];
  float* out = (float*)d_out;
  (void)in_sizes; (void)n_in; (void)out_size; (void)d_ws; (void)ws_size;
  hipLaunchKernelGGL(we_init, dim3(256), dim3(256), 0, stream);
  hipLaunchKernelGGL(we_lstm, dim3(512), dim3(256), 0, stream,
                     tokens, emb, Wk, Wr, bz, out);
  hipLaunchKernelGGL(we_proj, dim3(128 * TLEN / 32), dim3(256), 0, stream,
                     Wd, bd, out);
}

// Round 4
// 5407.534 us; speedup vs baseline: 1.5142x; 1.0718x over previous
//
#include <hip/hip_runtime.h>
#include <cstddef>

// WordEncoder: emb gather -> masked LSTM (T=1024) -> relu(h@Wd+bd)
// Recurrent kernel: 256 blocks = 16 batch-groups x 16 unit-groups, 1/CU.
// h exchanged via (tag|value) u64 packets at IC; tag = step+1 so the
// zero-initialized buffer is safe with no init kernel and across graph
// replays (slot-parity tags are monotone within a run). Packets fetched as
// dwordx4 (2 packets/transaction) issued before barrier X and left in
// flight while the x-part GEMM runs (counted-vmcnt pattern); tags checked
// after. y projection is a separate parallel kernel over the h history.

typedef unsigned int u32x4 __attribute__((ext_vector_type(4)));

constexpr int TLEN = 1024;
constexpr int EDIM = 128;
constexpr int UDIM = 256;
constexpr int DDIM = 256;

constexpr int BPB  = 8;    // batches per block
constexpr int UPB  = 16;   // units per block
constexpr int ZCOL = 64;   // z cols per block (4 gates x 16 units)
constexpr int HXROW = 432; // (384/32)*36 padded row (+4 per 32 -> bank spread)
constexpr int ZROW = 68;   // 64 + 4 pad

__device__ unsigned long long g_pkt[2][128][256]; // [parity][batch][unit]

__device__ __forceinline__ int pidx(int k) { return ((k >> 5) * 36) + (k & 31); }

__device__ __forceinline__ u32x4 pkt_load(const unsigned long long* p) {
  u32x4 v;
  asm volatile("global_load_dwordx4 %0, %1, off sc0 sc1" : "=v"(v) : "v"(p));
  return v;
}
#define PKT_WAIT4(a, b, c, d) \
  asm volatile("s_waitcnt vmcnt(0)" : "+v"(a), "+v"(b), "+v"(c), "+v"(d) :: "memory")

__global__ __launch_bounds__(256, 1) void we_lstm(
    const int* __restrict__ tokens, const float* __restrict__ emb,
    const float* __restrict__ Wk, const float* __restrict__ Wr,
    const float* __restrict__ bz, float* __restrict__ out)
{
  __shared__ float hx[2][BPB][HXROW]; // parity-dbuf [h(256)|x(128)], padded
  __shared__ float zs[BPB][ZROW];     // reduced z (pre-bias)
  __shared__ float bias_s[ZCOL];
  __shared__ int   tok_s[2][BPB];

  const int tid = threadIdx.x;
  const int bid = blockIdx.x;
  const int bg  = bid >> 4;
  const int ug  = bid & 15;
  const int b0  = bg * BPB;
  const int u0  = ug * UPB;

  // GEMM decomposition: 256 = 16 col-quads x 16 k-slices; 8 batch rows each.
  // k-space strided so i=0..3 -> h-part (k<256), i=4,5 -> x-part (k>=256):
  // k = ksl*4 + i*64 + j
  const int ksl = tid & 15;
  const int cq  = tid >> 4;

  // ---- prologue: weight slice into registers (24k x 4c per thread) ----
  float w[96];
#pragma unroll
  for (int i = 0; i < 6; ++i)
#pragma unroll
    for (int j = 0; j < 4; ++j) {
      const int k = ksl * 4 + i * 64 + j;
#pragma unroll
      for (int cc = 0; cc < 4; ++cc) {
        const int c   = cq * 4 + cc;
        const int col = ((c >> 4) << 8) + u0 + (c & 15);
        w[(i * 4 + j) * 4 + cc] =
            (k < UDIM) ? Wr[k * 1024 + col] : Wk[(k - UDIM) * 1024 + col];
      }
    }
  if (tid < ZCOL) bias_s[tid] = bz[((tid >> 4) << 8) + u0 + (tid & 15)];

  float creg = 0.f;
  const int gb = tid >> 4, gu = tid & 15;       // gates (tid<128)
  const int xb = tid >> 5, xe = (tid & 31) << 2; // x stage
  const int up = tid & 127, bq = (tid >> 7) * 4; // pkt stage: units 2up..2up+1

  for (int it = 0; it < TLEN; ++it) {
    const int cur = it & 1;
    if (tid < BPB) tok_s[cur][tid] = tokens[(b0 + tid) * TLEN + it];

    // ---- x gather -> LDS (compiler-managed wait; no asm loads in flight) ----
    const int tk = tokens[(b0 + xb) * TLEN + it];
    const float4 xv = *(const float4*)&emb[(size_t)tk * EDIM + xe];
    *(float4*)&hx[cur][xb][pidx(UDIM + xe)] = xv;

    // ---- issue packet loads; they stay in flight across barrier X ----
    u32x4 p0, p1, p2, p3;
    const unsigned want = (unsigned)it; // producer tag = step+1
    const int rp = (it + 1) & 1;        // == (it-1)&1
    if (it > 0) {
      p0 = pkt_load(&g_pkt[rp][b0 + bq + 0][2 * up]);
      p1 = pkt_load(&g_pkt[rp][b0 + bq + 1][2 * up]);
      p2 = pkt_load(&g_pkt[rp][b0 + bq + 2][2 * up]);
      p3 = pkt_load(&g_pkt[rp][b0 + bq + 3][2 * up]);
    }
    __syncthreads(); // X: x staged

    float acc[8][4];
#pragma unroll
    for (int r = 0; r < 8; ++r) {
      acc[r][0] = 0.f; acc[r][1] = 0.f; acc[r][2] = 0.f; acc[r][3] = 0.f;
    }
    // ---- x-part GEMM (i=4,5) hides the packet round-trip ----
#pragma unroll
    for (int i = 4; i < 6; ++i) {
      const int hoff = pidx(ksl * 4 + i * 64);
      float4 hv[8];
#pragma unroll
      for (int r = 0; r < 8; ++r) hv[r] = *(const float4*)&hx[cur][r][hoff];
#pragma unroll
      for (int j = 0; j < 4; ++j)
#pragma unroll
        for (int r = 0; r < 8; ++r) {
          const float hval = (j == 0) ? hv[r].x : (j == 1) ? hv[r].y
                             : (j == 2) ? hv[r].z : hv[r].w;
#pragma unroll
          for (int cc = 0; cc < 4; ++cc)
            acc[r][cc] += hval * w[(i * 4 + j) * 4 + cc];
        }
    }

    // ---- packet wait + tag check (+value-carrying retry, 1 RT per round) ----
    const int ho = pidx(2 * up);
    if (it > 0) {
      PKT_WAIT4(p0, p1, p2, p3);
      while (!((p0[1] == want) & (p0[3] == want) & (p1[1] == want) &
               (p1[3] == want) & (p2[1] == want) & (p2[3] == want) &
               (p3[1] == want) & (p3[3] == want))) {
        __builtin_amdgcn_s_sleep(1);
        p0 = pkt_load(&g_pkt[rp][b0 + bq + 0][2 * up]);
        p1 = pkt_load(&g_pkt[rp][b0 + bq + 1][2 * up]);
        p2 = pkt_load(&g_pkt[rp][b0 + bq + 2][2 * up]);
        p3 = pkt_load(&g_pkt[rp][b0 + bq + 3][2 * up]);
        PKT_WAIT4(p0, p1, p2, p3);
      }
      *(float2*)&hx[cur][bq + 0][ho] =
          make_float2(__uint_as_float(p0[0]), __uint_as_float(p0[2]));
      *(float2*)&hx[cur][bq + 1][ho] =
          make_float2(__uint_as_float(p1[0]), __uint_as_float(p1[2]));
      *(float2*)&hx[cur][bq + 2][ho] =
          make_float2(__uint_as_float(p2[0]), __uint_as_float(p2[2]));
      *(float2*)&hx[cur][bq + 3][ho] =
          make_float2(__uint_as_float(p3[0]), __uint_as_float(p3[2]));
    } else {
#pragma unroll
      for (int jj = 0; jj < 4; ++jj)
        *(float2*)&hx[cur][bq + jj][ho] = make_float2(0.f, 0.f);
    }
    __syncthreads(); // A: h staged

    // ---- h-part GEMM (i=0..3) ----
#pragma unroll
    for (int i = 0; i < 4; ++i) {
      const int hoff = pidx(ksl * 4 + i * 64);
      float4 hv[8];
#pragma unroll
      for (int r = 0; r < 8; ++r) hv[r] = *(const float4*)&hx[cur][r][hoff];
#pragma unroll
      for (int j = 0; j < 4; ++j)
#pragma unroll
        for (int r = 0; r < 8; ++r) {
          const float hval = (j == 0) ? hv[r].x : (j == 1) ? hv[r].y
                             : (j == 2) ? hv[r].z : hv[r].w;
#pragma unroll
          for (int cc = 0; cc < 4; ++cc)
            acc[r][cc] += hval * w[(i * 4 + j) * 4 + cc];
        }
    }

    // ---- in-wave k-reduce (16-lane xor butterfly) ----
#pragma unroll
    for (int r = 0; r < 8; ++r)
#pragma unroll
      for (int cc = 0; cc < 4; ++cc) {
        float v = acc[r][cc];
        v += __shfl_xor(v, 1);
        v += __shfl_xor(v, 2);
        v += __shfl_xor(v, 4);
        v += __shfl_xor(v, 8);
        acc[r][cc] = v;
      }
    if (ksl == 0) {
#pragma unroll
      for (int r = 0; r < 8; ++r)
        *(float4*)&zs[r][cq * 4] =
            make_float4(acc[r][0], acc[r][1], acc[r][2], acc[r][3]);
    }
    __syncthreads(); // B: zs ready

    // ---- gates: tid<128 owns (batch gb, unit u0+gu) ----
    if (tid < 128) {
      const float zi = zs[gb][gu]      + bias_s[gu];
      const float zf = zs[gb][16 + gu] + bias_s[16 + gu];
      const float zg = zs[gb][32 + gu] + bias_s[32 + gu];
      const float zo = zs[gb][48 + gu] + bias_s[48 + gu];
      const float gi = 1.f / (1.f + __expf(-zi));
      const float gf = 1.f / (1.f + __expf(-zf));
      const float gg = 1.f - 2.f / (1.f + __expf(2.f * zg)); // tanh
      const float go = 1.f / (1.f + __expf(-zo));
      const float cn = gf * creg + gi * gg;
      const float th = 1.f - 2.f / (1.f + __expf(2.f * cn));
      const float hn = go * th;
      const bool msk = (tok_s[cur][gb] != 0);
      const float hold = hx[cur][gb][pidx(u0 + gu)];
      const float h2 = msk ? hn : hold;
      creg = msk ? cn : creg;
      const unsigned long long pkt =
          ((unsigned long long)(unsigned)(it + 1) << 32) | __float_as_uint(h2);
      __hip_atomic_store(&g_pkt[cur][b0 + gb][u0 + gu], pkt, __ATOMIC_RELAXED,
                         __HIP_MEMORY_SCOPE_AGENT);
      __builtin_nontemporal_store(
          h2, &out[((size_t)(b0 + gb) * TLEN + it) * DDIM + u0 + gu]);
    }
    // no end barrier: staging of step it+1 writes hx[1-cur]; zs next written
    // only after barrier A(it+1); h ordering is packet-self-clocked.
  }
}

// y = relu(H @ Wd + bd), in place over d_out (h history -> y). 32 rows/block.
__global__ __launch_bounds__(256, 2) void we_proj(
    const float* __restrict__ Wd, const float* __restrict__ bd,
    float* __restrict__ out)
{
  __shared__ float hs[32][260];
  __shared__ float ws[32][260];
  __shared__ float bds[DDIM];

  const int tid = threadIdx.x;
  const size_t row0 = (size_t)blockIdx.x * 32;

#pragma unroll
  for (int j2 = 0; j2 < 8; ++j2) {
    const int idx = tid + j2 * 256;
    const int r = idx >> 6;
    const int cq = idx & 63;
    *(float4*)&hs[r][cq * 4] = *(const float4*)&out[(row0 + r) * DDIM + cq * 4];
  }
  bds[tid] = bd[tid];

  const int rg = tid >> 5;
  const int c0 = (tid & 31) * 8;
  float acc[4][8];
#pragma unroll
  for (int i = 0; i < 4; ++i)
#pragma unroll
    for (int c = 0; c < 8; ++c) acc[i][c] = 0.f;

  for (int kt = 0; kt < 8; ++kt) {
    __syncthreads();
#pragma unroll
    for (int j2 = 0; j2 < 8; ++j2) {
      const int idx = tid + j2 * 256;
      const int kk = idx >> 6;
      const int cq = idx & 63;
      *(float4*)&ws[kk][cq * 4] =
          *(const float4*)&Wd[(size_t)(kt * 32 + kk) * DDIM + cq * 4];
    }
    __syncthreads();
#pragma unroll
    for (int kk = 0; kk < 32; ++kk) {
      const float4 wv0 = *(const float4*)&ws[kk][c0];
      const float4 wv1 = *(const float4*)&ws[kk][c0 + 4];
#pragma unroll
      for (int i = 0; i < 4; ++i) {
        const float hval = hs[rg + i * 8][kt * 32 + kk];
        acc[i][0] += hval * wv0.x; acc[i][1] += hval * wv0.y;
        acc[i][2] += hval * wv0.z; acc[i][3] += hval * wv0.w;
        acc[i][4] += hval * wv1.x; acc[i][5] += hval * wv1.y;
        acc[i][6] += hval * wv1.z; acc[i][7] += hval * wv1.w;
      }
    }
  }
#pragma unroll
  for (int i = 0; i < 4; ++i) {
    float4 y0, y1;
    y0.x = fmaxf(acc[i][0] + bds[c0 + 0], 0.f);
    y0.y = fmaxf(acc[i][1] + bds[c0 + 1], 0.f);
    y0.z = fmaxf(acc[i][2] + bds[c0 + 2], 0.f);
    y0.w = fmaxf(acc[i][3] + bds[c0 + 3], 0.f);
    y1.x = fmaxf(acc[i][4] + bds[c0 + 4], 0.f);
    y1.y = fmaxf(acc[i][5] + bds[c0 + 5], 0.f);
    y1.z = fmaxf(acc[i][6] + bds[c0 + 6], 0.f);
    y1.w = fmaxf(acc[i][7] + bds[c0 + 7], 0.f);
    const size_t orow = (row0 + rg + i * 8) * DDIM;
    *(float4*)&out[orow + c0]     = y0;
    *(float4*)&out[orow + c0 + 4] = y1;
  }
}

extern "C" void kernel_launch(void* const* d_in, const int* in_sizes, int n_in,
                              void* d_out, int out_size, void* d_ws, size_t ws_size,
                              hipStream_t stream) {
  const int*   tokens = (const int*)d_in[0];
  const float* emb    = (const float*)d_in[1];
  const float* Wk     = (const float*)d_in[2];
  const float* Wr     = (const float*)d_in[3];
  const float* bz     = (const float*)d_in[4];
  const float* Wd     = (const float*)d_in[5];
  const float* bd     = (const float*)d_in[6];
  float* out = (float*)d_out;
  (void)in_sizes; (void)n_in; (void)out_size; (void)d_ws; (void)ws_size;
  hipLaunchKernelGGL(we_lstm, dim3(256), dim3(256), 0, stream,
                     tokens, emb, Wk, Wr, bz, out);
  hipLaunchKernelGGL(we_proj, dim3(128 * TLEN / 32), dim3(256), 0, stream,
                     Wd, bd, out);
}

// Round 6
// 4103.532 us; speedup vs baseline: 1.9954x; 1.3178x over previous
//
#include <hip/hip_runtime.h>
#include <cstddef>

// WordEncoder: emb gather -> masked LSTM (T=1024) -> relu(h@Wd+bd)
// Recurrent kernel: 256 blocks = 16 batch-groups x 16 unit-groups, 1/CU.
// h exchanged via (tag|value) u64 packets at IC (tag = step+1; zero-init
// buffer safe, benign across graph replays). k-reduce via DPP row_ror on the
// VALU pipe -- R6 uses __builtin_amdgcn_mov_dpp so the compiler inserts the
// required VALU->DPP hazard wait-states (R5's raw asm chain violated them).
// x/token prefetched one step ahead; packet loads issued after the x-part
// GEMM so the first tag check samples the IC when data is likely visible.

typedef unsigned int u32x4 __attribute__((ext_vector_type(4)));

constexpr int TLEN = 1024;
constexpr int EDIM = 128;
constexpr int UDIM = 256;
constexpr int DDIM = 256;

constexpr int BPB  = 8;    // batches per block
constexpr int UPB  = 16;   // units per block
constexpr int ZCOL = 64;   // z cols per block (4 gates x 16 units)
constexpr int HXROW = 432; // (384/32)*36 padded row (+4 per 32 -> bank spread)
constexpr int ZROW = 68;   // 64 + 4 pad

__device__ unsigned long long g_pkt[2][128][256]; // [parity][batch][unit]

__device__ __forceinline__ int pidx(int k) { return ((k >> 5) * 36) + (k & 31); }

__device__ __forceinline__ u32x4 pkt_load(const unsigned long long* p) {
  u32x4 v;
  asm volatile("global_load_dwordx4 %0, %1, off sc0 sc1" : "=v"(v) : "v"(p));
  return v;
}
#define PKT_WAIT4(a, b, c, d) \
  asm volatile("s_waitcnt vmcnt(0)" : "+v"(a), "+v"(b), "+v"(c), "+v"(d) :: "memory")

// Sum across the 16-lane DPP row (ksl groups == DPP rows). Pure VALU pipe.
// mov_dpp builtins let the compiler insert VALU->DPP hazard wait states.
__device__ __forceinline__ float rowsum16(float v) {
  v += __int_as_float(
      __builtin_amdgcn_mov_dpp(__float_as_int(v), 0x121, 0xf, 0xf, true));
  v += __int_as_float(
      __builtin_amdgcn_mov_dpp(__float_as_int(v), 0x122, 0xf, 0xf, true));
  v += __int_as_float(
      __builtin_amdgcn_mov_dpp(__float_as_int(v), 0x124, 0xf, 0xf, true));
  v += __int_as_float(
      __builtin_amdgcn_mov_dpp(__float_as_int(v), 0x128, 0xf, 0xf, true));
  return v;
}

__global__ __launch_bounds__(256, 1) void we_lstm(
    const int* __restrict__ tokens, const float* __restrict__ emb,
    const float* __restrict__ Wk, const float* __restrict__ Wr,
    const float* __restrict__ bz, float* __restrict__ out)
{
  __shared__ float hx[2][BPB][HXROW]; // parity-dbuf [h(256)|x(128)], padded
  __shared__ float zs[BPB][ZROW];     // reduced z (pre-bias)
  __shared__ float bias_s[ZCOL];

  const int tid = threadIdx.x;
  const int bid = blockIdx.x;
  const int bg  = bid >> 4;
  const int ug  = bid & 15;
  const int b0  = bg * BPB;
  const int u0  = ug * UPB;

  // GEMM decomposition: 256 = 16 col-quads x 16 k-slices; 8 batch rows each.
  // k = ksl*4 + i*64 + j ; i=0..3 -> h-part (k<256), i=4,5 -> x-part.
  const int ksl = tid & 15;
  const int cq  = tid >> 4;

  // ---- prologue: weight slice into registers (24k x 4c per thread) ----
  float w[96];
#pragma unroll
  for (int i = 0; i < 6; ++i)
#pragma unroll
    for (int j = 0; j < 4; ++j) {
      const int k = ksl * 4 + i * 64 + j;
#pragma unroll
      for (int cc = 0; cc < 4; ++cc) {
        const int c   = cq * 4 + cc;
        const int col = ((c >> 4) << 8) + u0 + (c & 15);
        w[(i * 4 + j) * 4 + cc] =
            (k < UDIM) ? Wr[k * 1024 + col] : Wk[(k - UDIM) * 1024 + col];
      }
    }
  if (tid < ZCOL) bias_s[tid] = bz[((tid >> 4) << 8) + u0 + (tid & 15)];

  float creg = 0.f;
  const int gb = tid >> 4, gu = tid & 15;        // gates (tid<128)
  const int xb = tid >> 5, xe = (tid & 31) << 2; // x stage
  const int up = tid & 127, bq = (tid >> 7) * 4; // pkt stage

  // ---- prefetch step 0 x and gate-token ----
  float4 xv = *(const float4*)&emb[(size_t)tokens[(b0 + xb) * TLEN] * EDIM + xe];
  int tk_g = (tid < 128) ? tokens[(b0 + gb) * TLEN] : 1;

  for (int it = 0; it < TLEN; ++it) {
    const int cur = it & 1;

    // ---- write prefetched x -> LDS ----
    *(float4*)&hx[cur][xb][pidx(UDIM + xe)] = xv;
    __syncthreads(); // X: x staged

    float acc[8][4];
#pragma unroll
    for (int r = 0; r < 8; ++r) {
      acc[r][0] = 0.f; acc[r][1] = 0.f; acc[r][2] = 0.f; acc[r][3] = 0.f;
    }
    // ---- x-part GEMM (i=4,5) ----
#pragma unroll
    for (int i = 4; i < 6; ++i) {
      const int hoff = pidx(ksl * 4 + i * 64);
      float4 hv[8];
#pragma unroll
      for (int r = 0; r < 8; ++r) hv[r] = *(const float4*)&hx[cur][r][hoff];
#pragma unroll
      for (int j = 0; j < 4; ++j)
#pragma unroll
        for (int r = 0; r < 8; ++r) {
          const float hval = (j == 0) ? hv[r].x : (j == 1) ? hv[r].y
                             : (j == 2) ? hv[r].z : hv[r].w;
#pragma unroll
          for (int cc = 0; cc < 4; ++cc)
            acc[r][cc] += hval * w[(i * 4 + j) * 4 + cc];
        }
    }

    // ---- issue packet loads (after x-GEMM: sample IC when data is fresh) ----
    u32x4 p0, p1, p2, p3;
    const unsigned want = (unsigned)it; // producer tag = step+1
    const int rp = (it + 1) & 1;        // == (it-1)&1
    if (it > 0) {
      p0 = pkt_load(&g_pkt[rp][b0 + bq + 0][2 * up]);
      p1 = pkt_load(&g_pkt[rp][b0 + bq + 1][2 * up]);
      p2 = pkt_load(&g_pkt[rp][b0 + bq + 2][2 * up]);
      p3 = pkt_load(&g_pkt[rp][b0 + bq + 3][2 * up]);
    }

    // ---- prefetch next-step x / gate-token (completes under packet wait) ----
    float4 xv_n;
    int tk_g_n = 1;
    if (it + 1 < TLEN) {
      const int tk_x = tokens[(b0 + xb) * TLEN + it + 1];
      xv_n = *(const float4*)&emb[(size_t)tk_x * EDIM + xe];
      if (tid < 128) tk_g_n = tokens[(b0 + gb) * TLEN + it + 1];
    }

    // ---- packet wait + tag check (value-carrying retry, 1 RT per round) ----
    const int ho = pidx(2 * up);
    if (it > 0) {
      PKT_WAIT4(p0, p1, p2, p3);
      while (!((p0[1] == want) & (p0[3] == want) & (p1[1] == want) &
               (p1[3] == want) & (p2[1] == want) & (p2[3] == want) &
               (p3[1] == want) & (p3[3] == want))) {
        __builtin_amdgcn_s_sleep(1);
        p0 = pkt_load(&g_pkt[rp][b0 + bq + 0][2 * up]);
        p1 = pkt_load(&g_pkt[rp][b0 + bq + 1][2 * up]);
        p2 = pkt_load(&g_pkt[rp][b0 + bq + 2][2 * up]);
        p3 = pkt_load(&g_pkt[rp][b0 + bq + 3][2 * up]);
        PKT_WAIT4(p0, p1, p2, p3);
      }
      *(float2*)&hx[cur][bq + 0][ho] =
          make_float2(__uint_as_float(p0[0]), __uint_as_float(p0[2]));
      *(float2*)&hx[cur][bq + 1][ho] =
          make_float2(__uint_as_float(p1[0]), __uint_as_float(p1[2]));
      *(float2*)&hx[cur][bq + 2][ho] =
          make_float2(__uint_as_float(p2[0]), __uint_as_float(p2[2]));
      *(float2*)&hx[cur][bq + 3][ho] =
          make_float2(__uint_as_float(p3[0]), __uint_as_float(p3[2]));
    } else {
#pragma unroll
      for (int jj = 0; jj < 4; ++jj)
        *(float2*)&hx[cur][bq + jj][ho] = make_float2(0.f, 0.f);
    }
    __syncthreads(); // A: h staged

    // ---- h-part GEMM (i=0..3) ----
#pragma unroll
    for (int i = 0; i < 4; ++i) {
      const int hoff = pidx(ksl * 4 + i * 64);
      float4 hv[8];
#pragma unroll
      for (int r = 0; r < 8; ++r) hv[r] = *(const float4*)&hx[cur][r][hoff];
#pragma unroll
      for (int j = 0; j < 4; ++j)
#pragma unroll
        for (int r = 0; r < 8; ++r) {
          const float hval = (j == 0) ? hv[r].x : (j == 1) ? hv[r].y
                             : (j == 2) ? hv[r].z : hv[r].w;
#pragma unroll
          for (int cc = 0; cc < 4; ++cc)
            acc[r][cc] += hval * w[(i * 4 + j) * 4 + cc];
        }
    }

    // ---- k-reduce via DPP row_ror (VALU pipe; ksl groups == DPP rows) ----
#pragma unroll
    for (int r = 0; r < 8; ++r)
#pragma unroll
      for (int cc = 0; cc < 4; ++cc)
        acc[r][cc] = rowsum16(acc[r][cc]);
    if (ksl == 0) {
#pragma unroll
      for (int r = 0; r < 8; ++r)
        *(float4*)&zs[r][cq * 4] =
            make_float4(acc[r][0], acc[r][1], acc[r][2], acc[r][3]);
    }
    __syncthreads(); // B: zs ready

    // ---- gates: tid<128 owns (batch gb, unit u0+gu) ----
    if (tid < 128) {
      const float zi = zs[gb][gu]      + bias_s[gu];
      const float zf = zs[gb][16 + gu] + bias_s[16 + gu];
      const float zg = zs[gb][32 + gu] + bias_s[32 + gu];
      const float zo = zs[gb][48 + gu] + bias_s[48 + gu];
      const float gi = 1.f / (1.f + __expf(-zi));
      const float gf = 1.f / (1.f + __expf(-zf));
      const float gg = 1.f - 2.f / (1.f + __expf(2.f * zg)); // tanh
      const float go = 1.f / (1.f + __expf(-zo));
      const float cn = gf * creg + gi * gg;
      const float th = 1.f - 2.f / (1.f + __expf(2.f * cn));
      const float hn = go * th;
      const bool msk = (tk_g != 0);
      const float hold = hx[cur][gb][pidx(u0 + gu)];
      const float h2 = msk ? hn : hold;
      creg = msk ? cn : creg;
      const unsigned long long pkt =
          ((unsigned long long)(unsigned)(it + 1) << 32) | __float_as_uint(h2);
      __hip_atomic_store(&g_pkt[cur][b0 + gb][u0 + gu], pkt, __ATOMIC_RELAXED,
                         __HIP_MEMORY_SCOPE_AGENT);
      __builtin_nontemporal_store(
          h2, &out[((size_t)(b0 + gb) * TLEN + it) * DDIM + u0 + gu]);
    }
    xv = xv_n;
    tk_g = tk_g_n;
    // no end barrier: staging of step it+1 writes hx[1-cur]; zs next written
    // only after barrier A(it+1); h ordering is packet-self-clocked.
  }
}

// y = relu(H @ Wd + bd), in place over d_out (h history -> y). 32 rows/block.
__global__ __launch_bounds__(256, 2) void we_proj(
    const float* __restrict__ Wd, const float* __restrict__ bd,
    float* __restrict__ out)
{
  __shared__ float hs[32][260];
  __shared__ float ws[32][260];
  __shared__ float bds[DDIM];

  const int tid = threadIdx.x;
  const size_t row0 = (size_t)blockIdx.x * 32;

#pragma unroll
  for (int j2 = 0; j2 < 8; ++j2) {
    const int idx = tid + j2 * 256;
    const int r = idx >> 6;
    const int cq = idx & 63;
    *(float4*)&hs[r][cq * 4] = *(const float4*)&out[(row0 + r) * DDIM + cq * 4];
  }
  bds[tid] = bd[tid];

  const int rg = tid >> 5;
  const int c0 = (tid & 31) * 8;
  float acc[4][8];
#pragma unroll
  for (int i = 0; i < 4; ++i)
#pragma unroll
    for (int c = 0; c < 8; ++c) acc[i][c] = 0.f;

  for (int kt = 0; kt < 8; ++kt) {
    __syncthreads();
#pragma unroll
    for (int j2 = 0; j2 < 8; ++j2) {
      const int idx = tid + j2 * 256;
      const int kk = idx >> 6;
      const int cq = idx & 63;
      *(float4*)&ws[kk][cq * 4] =
          *(const float4*)&Wd[(size_t)(kt * 32 + kk) * DDIM + cq * 4];
    }
    __syncthreads();
#pragma unroll
    for (int kk = 0; kk < 32; ++kk) {
      const float4 wv0 = *(const float4*)&ws[kk][c0];
      const float4 wv1 = *(const float4*)&ws[kk][c0 + 4];
#pragma unroll
      for (int i = 0; i < 4; ++i) {
        const float hval = hs[rg + i * 8][kt * 32 + kk];
        acc[i][0] += hval * wv0.x; acc[i][1] += hval * wv0.y;
        acc[i][2] += hval * wv0.z; acc[i][3] += hval * wv0.w;
        acc[i][4] += hval * wv1.x; acc[i][5] += hval * wv1.y;
        acc[i][6] += hval * wv1.z; acc[i][7] += hval * wv1.w;
      }
    }
  }
#pragma unroll
  for (int i = 0; i < 4; ++i) {
    float4 y0, y1;
    y0.x = fmaxf(acc[i][0] + bds[c0 + 0], 0.f);
    y0.y = fmaxf(acc[i][1] + bds[c0 + 1], 0.f);
    y0.z = fmaxf(acc[i][2] + bds[c0 + 2], 0.f);
    y0.w = fmaxf(acc[i][3] + bds[c0 + 3], 0.f);
    y1.x = fmaxf(acc[i][4] + bds[c0 + 4], 0.f);
    y1.y = fmaxf(acc[i][5] + bds[c0 + 5], 0.f);
    y1.z = fmaxf(acc[i][6] + bds[c0 + 6], 0.f);
    y1.w = fmaxf(acc[i][7] + bds[c0 + 7], 0.f);
    const size_t orow = (row0 + rg + i * 8) * DDIM;
    *(float4*)&out[orow + c0]     = y0;
    *(float4*)&out[orow + c0 + 4] = y1;
  }
}

extern "C" void kernel_launch(void* const* d_in, const int* in_sizes, int n_in,
                              void* d_out, int out_size, void* d_ws, size_t ws_size,
                              hipStream_t stream) {
  const int*   tokens = (const int*)d_in[0];
  const float* emb    = (const float*)d_in[1];
  const float* Wk     = (const float*)d_in[2];
  const float* Wr     = (const float*)d_in[3];
  const float* bz     = (const float*)d_in[4];
  const float* Wd     = (const float*)d_in[5];
  const float* bd     = (const float*)d_in[6];
  float* out = (float*)d_out;
  (void)in_sizes; (void)n_in; (void)out_size; (void)d_ws; (void)ws_size;
  hipLaunchKernelGGL(we_lstm, dim3(256), dim3(256), 0, stream,
                     tokens, emb, Wk, Wr, bz, out);
  hipLaunchKernelGGL(we_proj, dim3(128 * TLEN / 32), dim3(256), 0, stream,
                     Wd, bd, out);
}

// Round 7
// 3947.596 us; speedup vs baseline: 2.0742x; 1.0395x over previous
//
#include <hip/hip_runtime.h>
#include <cstddef>

// WordEncoder: emb gather -> masked LSTM (T=1024) -> relu(h@Wd+bd)
// Recurrent kernel: 256 blocks = 16 batch-groups x 16 unit-groups, 1/CU.
// R7: groups remapped so a sync group's 16 blocks share bid%8 (one XCD under
// round-robin dispatch -- perf heuristic only). Producers dual-publish each
// (tag|h) packet: plain store -> g_pktA (XCD-local L2, ~250cy RT) and
// agent-scope store -> g_pktB (IC mirror). Consumers poll A with sc0 loads;
// after 8 failed rounds they permanently downgrade to the IC mirror, so
// correctness/liveness never depends on block placement. Packets are
// self-validating (tag = step+1), zero-init safe, replay-alias benign.

typedef unsigned int u32x4 __attribute__((ext_vector_type(4)));

constexpr int TLEN = 1024;
constexpr int EDIM = 128;
constexpr int UDIM = 256;
constexpr int DDIM = 256;

constexpr int BPB  = 8;    // batches per block
constexpr int UPB  = 16;   // units per block
constexpr int ZCOL = 64;   // z cols per block (4 gates x 16 units)
constexpr int HXROW = 432; // (384/32)*36 padded row (+4 per 32 -> bank spread)
constexpr int ZROW = 68;   // 64 + 4 pad

__device__ unsigned long long g_pktA[2][128][256]; // XCD-local path (L2)
__device__ unsigned long long g_pktB[2][128][256]; // device-coherent mirror (IC)

__device__ __forceinline__ int pidx(int k) { return ((k >> 5) * 36) + (k & 31); }

__device__ __forceinline__ u32x4 pkt_load_ic(const unsigned long long* p) {
  u32x4 v;
  asm volatile("global_load_dwordx4 %0, %1, off sc0 sc1" : "=v"(v) : "v"(p));
  return v;
}
__device__ __forceinline__ u32x4 pkt_load_l2(const unsigned long long* p) {
  u32x4 v; // sc0: bypass L1, hit the XCD-coherent L2
  asm volatile("global_load_dwordx4 %0, %1, off sc0" : "=v"(v) : "v"(p));
  return v;
}
#define PKT_WAIT4(a, b, c, d) \
  asm volatile("s_waitcnt vmcnt(0)" : "+v"(a), "+v"(b), "+v"(c), "+v"(d) :: "memory")
#define TAGS_OK() \
  ((p0[1] == want) & (p0[3] == want) & (p1[1] == want) & (p1[3] == want) & \
   (p2[1] == want) & (p2[3] == want) & (p3[1] == want) & (p3[3] == want))

// Sum across the 16-lane DPP row (ksl groups == DPP rows). Pure VALU pipe.
__device__ __forceinline__ float rowsum16(float v) {
  v += __int_as_float(
      __builtin_amdgcn_mov_dpp(__float_as_int(v), 0x121, 0xf, 0xf, true));
  v += __int_as_float(
      __builtin_amdgcn_mov_dpp(__float_as_int(v), 0x122, 0xf, 0xf, true));
  v += __int_as_float(
      __builtin_amdgcn_mov_dpp(__float_as_int(v), 0x124, 0xf, 0xf, true));
  v += __int_as_float(
      __builtin_amdgcn_mov_dpp(__float_as_int(v), 0x128, 0xf, 0xf, true));
  return v;
}

__global__ __launch_bounds__(256, 1) void we_lstm(
    const int* __restrict__ tokens, const float* __restrict__ emb,
    const float* __restrict__ Wk, const float* __restrict__ Wr,
    const float* __restrict__ bz, float* __restrict__ out)
{
  __shared__ float hx[2][BPB][HXROW]; // parity-dbuf [h(256)|x(128)], padded
  __shared__ float zs[BPB][ZROW];     // reduced z (pre-bias)
  __shared__ float bias_s[ZCOL];

  const int tid = threadIdx.x;
  const int bid = blockIdx.x;
  // group remap: all 16 blocks of a bg share bid%8 -> one XCD if round-robin
  const int bg  = ((bid & 7) << 1) | ((bid >> 3) & 1);
  const int ug  = bid >> 4;
  const int b0  = bg * BPB;
  const int u0  = ug * UPB;

  // GEMM decomposition: 256 = 16 col-quads x 16 k-slices; 8 batch rows each.
  // k = ksl*4 + i*64 + j ; i=0..3 -> h-part (k<256), i=4,5 -> x-part.
  const int ksl = tid & 15;
  const int cq  = tid >> 4;

  // ---- prologue: weight slice into registers (24k x 4c per thread) ----
  float w[96];
#pragma unroll
  for (int i = 0; i < 6; ++i)
#pragma unroll
    for (int j = 0; j < 4; ++j) {
      const int k = ksl * 4 + i * 64 + j;
#pragma unroll
      for (int cc = 0; cc < 4; ++cc) {
        const int c   = cq * 4 + cc;
        const int col = ((c >> 4) << 8) + u0 + (c & 15);
        w[(i * 4 + j) * 4 + cc] =
            (k < UDIM) ? Wr[k * 1024 + col] : Wk[(k - UDIM) * 1024 + col];
      }
    }
  if (tid < ZCOL) bias_s[tid] = bz[((tid >> 4) << 8) + u0 + (tid & 15)];

  float creg = 0.f;
  const int gb = tid >> 4, gu = tid & 15;        // gates (tid<128)
  const int xb = tid >> 5, xe = (tid & 31) << 2; // x stage
  const int up = tid & 127, bq = (tid >> 7) * 4; // pkt stage

  bool use_local = true; // self-tuning exchange path (sticky downgrade)

  // ---- prefetch step 0 x and gate-token ----
  float4 xv = *(const float4*)&emb[(size_t)tokens[(b0 + xb) * TLEN] * EDIM + xe];
  int tk_g = (tid < 128) ? tokens[(b0 + gb) * TLEN] : 1;

  for (int it = 0; it < TLEN; ++it) {
    const int cur = it & 1;

    // ---- write prefetched x -> LDS ----
    *(float4*)&hx[cur][xb][pidx(UDIM + xe)] = xv;
    __syncthreads(); // X: x staged

    float acc[8][4];
#pragma unroll
    for (int r = 0; r < 8; ++r) {
      acc[r][0] = 0.f; acc[r][1] = 0.f; acc[r][2] = 0.f; acc[r][3] = 0.f;
    }
    // ---- x-part GEMM (i=4,5) ----
#pragma unroll
    for (int i = 4; i < 6; ++i) {
      const int hoff = pidx(ksl * 4 + i * 64);
      float4 hv[8];
#pragma unroll
      for (int r = 0; r < 8; ++r) hv[r] = *(const float4*)&hx[cur][r][hoff];
#pragma unroll
      for (int j = 0; j < 4; ++j)
#pragma unroll
        for (int r = 0; r < 8; ++r) {
          const float hval = (j == 0) ? hv[r].x : (j == 1) ? hv[r].y
                             : (j == 2) ? hv[r].z : hv[r].w;
#pragma unroll
          for (int cc = 0; cc < 4; ++cc)
            acc[r][cc] += hval * w[(i * 4 + j) * 4 + cc];
        }
    }

    // ---- issue packet loads (after x-GEMM: sample when data is fresh) ----
    u32x4 p0, p1, p2, p3;
    const unsigned want = (unsigned)it; // producer tag = step+1
    const int rp = (it + 1) & 1;        // == (it-1)&1
    if (it > 0) {
      if (use_local) {
        p0 = pkt_load_l2(&g_pktA[rp][b0 + bq + 0][2 * up]);
        p1 = pkt_load_l2(&g_pktA[rp][b0 + bq + 1][2 * up]);
        p2 = pkt_load_l2(&g_pktA[rp][b0 + bq + 2][2 * up]);
        p3 = pkt_load_l2(&g_pktA[rp][b0 + bq + 3][2 * up]);
      } else {
        p0 = pkt_load_ic(&g_pktB[rp][b0 + bq + 0][2 * up]);
        p1 = pkt_load_ic(&g_pktB[rp][b0 + bq + 1][2 * up]);
        p2 = pkt_load_ic(&g_pktB[rp][b0 + bq + 2][2 * up]);
        p3 = pkt_load_ic(&g_pktB[rp][b0 + bq + 3][2 * up]);
      }
    }

    // ---- prefetch next-step x / gate-token (completes under packet wait) ----
    float4 xv_n;
    int tk_g_n = 1;
    if (it + 1 < TLEN) {
      const int tk_x = tokens[(b0 + xb) * TLEN + it + 1];
      xv_n = *(const float4*)&emb[(size_t)tk_x * EDIM + xe];
      if (tid < 128) tk_g_n = tokens[(b0 + gb) * TLEN + it + 1];
    }

    // ---- packet resolve: L2 fast path with sticky IC fallback ----
    const int ho = pidx(2 * up);
    if (it > 0) {
      PKT_WAIT4(p0, p1, p2, p3);
      bool ok = TAGS_OK();
      if (use_local) {
        int rounds = 0;
        while (!ok && rounds < 8) {
          __builtin_amdgcn_s_sleep(1);
          p0 = pkt_load_l2(&g_pktA[rp][b0 + bq + 0][2 * up]);
          p1 = pkt_load_l2(&g_pktA[rp][b0 + bq + 1][2 * up]);
          p2 = pkt_load_l2(&g_pktA[rp][b0 + bq + 2][2 * up]);
          p3 = pkt_load_l2(&g_pktA[rp][b0 + bq + 3][2 * up]);
          PKT_WAIT4(p0, p1, p2, p3);
          ok = TAGS_OK();
          ++rounds;
        }
        if (!ok) use_local = false; // cross-XCD placement: downgrade for good
      }
      while (!ok) {
        p0 = pkt_load_ic(&g_pktB[rp][b0 + bq + 0][2 * up]);
        p1 = pkt_load_ic(&g_pktB[rp][b0 + bq + 1][2 * up]);
        p2 = pkt_load_ic(&g_pktB[rp][b0 + bq + 2][2 * up]);
        p3 = pkt_load_ic(&g_pktB[rp][b0 + bq + 3][2 * up]);
        PKT_WAIT4(p0, p1, p2, p3);
        ok = TAGS_OK();
        if (!ok) __builtin_amdgcn_s_sleep(1);
      }
      *(float2*)&hx[cur][bq + 0][ho] =
          make_float2(__uint_as_float(p0[0]), __uint_as_float(p0[2]));
      *(float2*)&hx[cur][bq + 1][ho] =
          make_float2(__uint_as_float(p1[0]), __uint_as_float(p1[2]));
      *(float2*)&hx[cur][bq + 2][ho] =
          make_float2(__uint_as_float(p2[0]), __uint_as_float(p2[2]));
      *(float2*)&hx[cur][bq + 3][ho] =
          make_float2(__uint_as_float(p3[0]), __uint_as_float(p3[2]));
    } else {
#pragma unroll
      for (int jj = 0; jj < 4; ++jj)
        *(float2*)&hx[cur][bq + jj][ho] = make_float2(0.f, 0.f);
    }
    __syncthreads(); // A: h staged

    // ---- h-part GEMM (i=0..3) ----
#pragma unroll
    for (int i = 0; i < 4; ++i) {
      const int hoff = pidx(ksl * 4 + i * 64);
      float4 hv[8];
#pragma unroll
      for (int r = 0; r < 8; ++r) hv[r] = *(const float4*)&hx[cur][r][hoff];
#pragma unroll
      for (int j = 0; j < 4; ++j)
#pragma unroll
        for (int r = 0; r < 8; ++r) {
          const float hval = (j == 0) ? hv[r].x : (j == 1) ? hv[r].y
                             : (j == 2) ? hv[r].z : hv[r].w;
#pragma unroll
          for (int cc = 0; cc < 4; ++cc)
            acc[r][cc] += hval * w[(i * 4 + j) * 4 + cc];
        }
    }

    // ---- k-reduce via DPP row_ror (VALU pipe; ksl groups == DPP rows) ----
#pragma unroll
    for (int r = 0; r < 8; ++r)
#pragma unroll
      for (int cc = 0; cc < 4; ++cc)
        acc[r][cc] = rowsum16(acc[r][cc]);
    if (ksl == 0) {
#pragma unroll
      for (int r = 0; r < 8; ++r)
        *(float4*)&zs[r][cq * 4] =
            make_float4(acc[r][0], acc[r][1], acc[r][2], acc[r][3]);
    }
    __syncthreads(); // B: zs ready

    // ---- gates: tid<128 owns (batch gb, unit u0+gu) ----
    if (tid < 128) {
      const float zi = zs[gb][gu]      + bias_s[gu];
      const float zf = zs[gb][16 + gu] + bias_s[16 + gu];
      const float zg = zs[gb][32 + gu] + bias_s[32 + gu];
      const float zo = zs[gb][48 + gu] + bias_s[48 + gu];
      const float gi = 1.f / (1.f + __expf(-zi));
      const float gf = 1.f / (1.f + __expf(-zf));
      const float gg = 1.f - 2.f / (1.f + __expf(2.f * zg)); // tanh
      const float go = 1.f / (1.f + __expf(-zo));
      const float cn = gf * creg + gi * gg;
      const float th = 1.f - 2.f / (1.f + __expf(2.f * cn));
      const float hn = go * th;
      const bool msk = (tk_g != 0);
      const float hold = hx[cur][gb][pidx(u0 + gu)];
      const float h2 = msk ? hn : hold;
      creg = msk ? cn : creg;
      const unsigned long long pkt =
          ((unsigned long long)(unsigned)(it + 1) << 32) | __float_as_uint(h2);
      // dual publish: XCD-local L2 copy + device-coherent IC mirror
      __hip_atomic_store(&g_pktA[cur][b0 + gb][u0 + gu], pkt, __ATOMIC_RELAXED,
                         __HIP_MEMORY_SCOPE_WORKGROUP);
      __hip_atomic_store(&g_pktB[cur][b0 + gb][u0 + gu], pkt, __ATOMIC_RELAXED,
                         __HIP_MEMORY_SCOPE_AGENT);
      __builtin_nontemporal_store(
          h2, &out[((size_t)(b0 + gb) * TLEN + it) * DDIM + u0 + gu]);
    }
    xv = xv_n;
    tk_g = tk_g_n;
    // no end barrier: staging of step it+1 writes hx[1-cur]; zs next written
    // only after barrier A(it+1); h ordering is packet-self-clocked.
  }
}

// y = relu(H @ Wd + bd), in place over d_out (h history -> y). 32 rows/block.
__global__ __launch_bounds__(256, 2) void we_proj(
    const float* __restrict__ Wd, const float* __restrict__ bd,
    float* __restrict__ out)
{
  __shared__ float hs[32][260];
  __shared__ float ws[32][260];
  __shared__ float bds[DDIM];

  const int tid = threadIdx.x;
  const size_t row0 = (size_t)blockIdx.x * 32;

#pragma unroll
  for (int j2 = 0; j2 < 8; ++j2) {
    const int idx = tid + j2 * 256;
    const int r = idx >> 6;
    const int cq = idx & 63;
    *(float4*)&hs[r][cq * 4] = *(const float4*)&out[(row0 + r) * DDIM + cq * 4];
  }
  bds[tid] = bd[tid];

  const int rg = tid >> 5;
  const int c0 = (tid & 31) * 8;
  float acc[4][8];
#pragma unroll
  for (int i = 0; i < 4; ++i)
#pragma unroll
    for (int c = 0; c < 8; ++c) acc[i][c] = 0.f;

  for (int kt = 0; kt < 8; ++kt) {
    __syncthreads();
#pragma unroll
    for (int j2 = 0; j2 < 8; ++j2) {
      const int idx = tid + j2 * 256;
      const int kk = idx >> 6;
      const int cq = idx & 63;
      *(float4*)&ws[kk][cq * 4] =
          *(const float4*)&Wd[(size_t)(kt * 32 + kk) * DDIM + cq * 4];
    }
    __syncthreads();
#pragma unroll
    for (int kk = 0; kk < 32; ++kk) {
      const float4 wv0 = *(const float4*)&ws[kk][c0];
      const float4 wv1 = *(const float4*)&ws[kk][c0 + 4];
#pragma unroll
      for (int i = 0; i < 4; ++i) {
        const float hval = hs[rg + i * 8][kt * 32 + kk];
        acc[i][0] += hval * wv0.x; acc[i][1] += hval * wv0.y;
        acc[i][2] += hval * wv0.z; acc[i][3] += hval * wv0.w;
        acc[i][4] += hval * wv1.x; acc[i][5] += hval * wv1.y;
        acc[i][6] += hval * wv1.z; acc[i][7] += hval * wv1.w;
      }
    }
  }
#pragma unroll
  for (int i = 0; i < 4; ++i) {
    float4 y0, y1;
    y0.x = fmaxf(acc[i][0] + bds[c0 + 0], 0.f);
    y0.y = fmaxf(acc[i][1] + bds[c0 + 1], 0.f);
    y0.z = fmaxf(acc[i][2] + bds[c0 + 2], 0.f);
    y0.w = fmaxf(acc[i][3] + bds[c0 + 3], 0.f);
    y1.x = fmaxf(acc[i][4] + bds[c0 + 4], 0.f);
    y1.y = fmaxf(acc[i][5] + bds[c0 + 5], 0.f);
    y1.z = fmaxf(acc[i][6] + bds[c0 + 6], 0.f);
    y1.w = fmaxf(acc[i][7] + bds[c0 + 7], 0.f);
    const size_t orow = (row0 + rg + i * 8) * DDIM;
    *(float4*)&out[orow + c0]     = y0;
    *(float4*)&out[orow + c0 + 4] = y1;
  }
}

extern "C" void kernel_launch(void* const* d_in, const int* in_sizes, int n_in,
                              void* d_out, int out_size, void* d_ws, size_t ws_size,
                              hipStream_t stream) {
  const int*   tokens = (const int*)d_in[0];
  const float* emb    = (const float*)d_in[1];
  const float* Wk     = (const float*)d_in[2];
  const float* Wr     = (const float*)d_in[3];
  const float* bz     = (const float*)d_in[4];
  const float* Wd     = (const float*)d_in[5];
  const float* bd     = (const float*)d_in[6];
  float* out = (float*)d_out;
  (void)in_sizes; (void)n_in; (void)out_size; (void)d_ws; (void)ws_size;
  hipLaunchKernelGGL(we_lstm, dim3(256), dim3(256), 0, stream,
                     tokens, emb, Wk, Wr, bz, out);
  hipLaunchKernelGGL(we_proj, dim3(128 * TLEN / 32), dim3(256), 0, stream,
                     Wd, bd, out);
}

// Round 8
// 3695.643 us; speedup vs baseline: 2.2156x; 1.0682x over previous
//
#include <hip/hip_runtime.h>
#include <cstddef>

// WordEncoder: emb gather -> masked LSTM (T=1024) -> relu(h@Wd+bd)
// R8: 512 blocks = 16 batch-groups x 32 unit-groups, 2 blocks/CU carrying
// TWO INDEPENDENT recurrence chains per CU -- while one chain waits in its
// publish->poll latency window, the other's waves issue GEMM on the same
// SIMDs. Group remap keeps each sync group's 32 blocks on one XCD
// (L2-local exchange, proven R7) and makes co-resident pairs carry
// different groups. Exchange: dual-published (tag|h) packets; sc0 L2 poll
// with sticky IC fallback -- correctness never depends on placement.

typedef unsigned int u32x4 __attribute__((ext_vector_type(4)));

constexpr int TLEN = 1024;
constexpr int EDIM = 128;
constexpr int UDIM = 256;
constexpr int DDIM = 256;

constexpr int BPB  = 8;    // batches per block
constexpr int UPB  = 8;    // units per block
constexpr int ZCOL = 32;   // z cols per block (4 gates x 8 units)
constexpr int HXROW = 432; // (384/32)*36 padded row (+4 per 32 -> bank spread)
constexpr int ZROW = 36;   // 32 + 4 pad

__device__ unsigned long long g_pktA[2][128][256]; // XCD-local path (L2)
__device__ unsigned long long g_pktB[2][128][256]; // device-coherent mirror (IC)

__device__ __forceinline__ int pidx(int k) { return ((k >> 5) * 36) + (k & 31); }

__device__ __forceinline__ u32x4 pkt_load_ic(const unsigned long long* p) {
  u32x4 v;
  asm volatile("global_load_dwordx4 %0, %1, off sc0 sc1" : "=v"(v) : "v"(p));
  return v;
}
__device__ __forceinline__ u32x4 pkt_load_l2(const unsigned long long* p) {
  u32x4 v; // sc0: bypass L1, hit the XCD-coherent L2
  asm volatile("global_load_dwordx4 %0, %1, off sc0" : "=v"(v) : "v"(p));
  return v;
}
#define PKT_WAIT4(a, b, c, d) \
  asm volatile("s_waitcnt vmcnt(0)" : "+v"(a), "+v"(b), "+v"(c), "+v"(d) :: "memory")
#define TAGS_OK() \
  ((p0[1] == want) & (p0[3] == want) & (p1[1] == want) & (p1[3] == want) & \
   (p2[1] == want) & (p2[3] == want) & (p3[1] == want) & (p3[3] == want))

// Sum across the 16-lane DPP row (ksl groups == DPP rows). Pure VALU pipe.
__device__ __forceinline__ float rowsum16(float v) {
  v += __int_as_float(
      __builtin_amdgcn_mov_dpp(__float_as_int(v), 0x121, 0xf, 0xf, true));
  v += __int_as_float(
      __builtin_amdgcn_mov_dpp(__float_as_int(v), 0x122, 0xf, 0xf, true));
  v += __int_as_float(
      __builtin_amdgcn_mov_dpp(__float_as_int(v), 0x124, 0xf, 0xf, true));
  v += __int_as_float(
      __builtin_amdgcn_mov_dpp(__float_as_int(v), 0x128, 0xf, 0xf, true));
  return v;
}

__global__ __launch_bounds__(256, 2) void we_lstm(
    const int* __restrict__ tokens, const float* __restrict__ emb,
    const float* __restrict__ Wk, const float* __restrict__ Wr,
    const float* __restrict__ bz, float* __restrict__ out)
{
  __shared__ float hx[2][BPB][HXROW]; // parity-dbuf [h(256)|x(128)], padded
  __shared__ float zs[BPB][ZROW];     // reduced z (pre-bias)
  __shared__ float bias_s[ZCOL];

  const int tid = threadIdx.x;
  const int bid = blockIdx.x;
  // Group remap: a bg's 32 blocks share bid%8 (one XCD under round-robin);
  // co-resident pair (bid, bid+256) -> same XCD/CU, DIFFERENT bg (bit8).
  const int bg  = ((bid & 7) << 1) | ((bid >> 8) & 1);
  const int ug  = (bid >> 3) & 31;
  const int b0  = bg * BPB;
  const int u0  = ug * UPB;

  // GEMM decomposition: 256 = 2 row-halves x 8 col-quads x 16 k-slices;
  // 4 batch rows per thread. k = ksl*4 + i*64 + j ; i<4 h-part, i>=4 x-part.
  const int ksl = tid & 15;
  const int cq  = (tid >> 4) & 7;
  const int bh  = tid >> 7;

  // ---- prologue: weight slice into registers (24k x 4c per thread) ----
  float w[96];
#pragma unroll
  for (int i = 0; i < 6; ++i)
#pragma unroll
    for (int j = 0; j < 4; ++j) {
      const int k = ksl * 4 + i * 64 + j;
#pragma unroll
      for (int cc = 0; cc < 4; ++cc) {
        const int c   = cq * 4 + cc;
        const int col = ((c >> 3) << 8) + u0 + (c & 7);
        w[(i * 4 + j) * 4 + cc] =
            (k < UDIM) ? Wr[k * 1024 + col] : Wk[(k - UDIM) * 1024 + col];
      }
    }
  if (tid < ZCOL) bias_s[tid] = bz[((tid >> 3) << 8) + u0 + (tid & 7)];

  float creg = 0.f;
  const int gb = tid >> 3, gu = tid & 7;         // gates (tid<64)
  const int xb = tid >> 5, xe = (tid & 31) << 2; // x stage
  const int up = tid & 127, bq = (tid >> 7) * 4; // pkt stage

  bool use_local = true; // self-tuning exchange path (sticky downgrade)

  // ---- prefetch step 0 x and gate-token ----
  float4 xv = *(const float4*)&emb[(size_t)tokens[(b0 + xb) * TLEN] * EDIM + xe];
  int tk_g = (tid < 64) ? tokens[(b0 + gb) * TLEN] : 1;

  for (int it = 0; it < TLEN; ++it) {
    const int cur = it & 1;

    // ---- write prefetched x -> LDS ----
    *(float4*)&hx[cur][xb][pidx(UDIM + xe)] = xv;
    __syncthreads(); // X: x staged

    float acc[4][4];
#pragma unroll
    for (int r = 0; r < 4; ++r) {
      acc[r][0] = 0.f; acc[r][1] = 0.f; acc[r][2] = 0.f; acc[r][3] = 0.f;
    }
    // ---- x-part GEMM (i=4,5) ----
#pragma unroll
    for (int i = 4; i < 6; ++i) {
      const int hoff = pidx(ksl * 4 + i * 64);
      float4 hv[4];
#pragma unroll
      for (int r = 0; r < 4; ++r)
        hv[r] = *(const float4*)&hx[cur][bh * 4 + r][hoff];
#pragma unroll
      for (int j = 0; j < 4; ++j)
#pragma unroll
        for (int r = 0; r < 4; ++r) {
          const float hval = (j == 0) ? hv[r].x : (j == 1) ? hv[r].y
                             : (j == 2) ? hv[r].z : hv[r].w;
#pragma unroll
          for (int cc = 0; cc < 4; ++cc)
            acc[r][cc] += hval * w[(i * 4 + j) * 4 + cc];
        }
    }

    // ---- issue packet loads (after x-GEMM: sample when data is fresh) ----
    u32x4 p0, p1, p2, p3;
    const unsigned want = (unsigned)it; // producer tag = step+1
    const int rp = (it + 1) & 1;        // == (it-1)&1
    if (it > 0) {
      if (use_local) {
        p0 = pkt_load_l2(&g_pktA[rp][b0 + bq + 0][2 * up]);
        p1 = pkt_load_l2(&g_pktA[rp][b0 + bq + 1][2 * up]);
        p2 = pkt_load_l2(&g_pktA[rp][b0 + bq + 2][2 * up]);
        p3 = pkt_load_l2(&g_pktA[rp][b0 + bq + 3][2 * up]);
      } else {
        p0 = pkt_load_ic(&g_pktB[rp][b0 + bq + 0][2 * up]);
        p1 = pkt_load_ic(&g_pktB[rp][b0 + bq + 1][2 * up]);
        p2 = pkt_load_ic(&g_pktB[rp][b0 + bq + 2][2 * up]);
        p3 = pkt_load_ic(&g_pktB[rp][b0 + bq + 3][2 * up]);
      }
    }

    // ---- prefetch next-step x / gate-token (completes under packet wait) ----
    float4 xv_n;
    int tk_g_n = 1;
    if (it + 1 < TLEN) {
      const int tk_x = tokens[(b0 + xb) * TLEN + it + 1];
      xv_n = *(const float4*)&emb[(size_t)tk_x * EDIM + xe];
      if (tid < 64) tk_g_n = tokens[(b0 + gb) * TLEN + it + 1];
    }

    // ---- packet resolve: L2 fast path with sticky IC fallback ----
    const int ho = pidx(2 * up);
    if (it > 0) {
      PKT_WAIT4(p0, p1, p2, p3);
      bool ok = TAGS_OK();
      if (use_local) {
        int rounds = 0;
        while (!ok && rounds < 8) {
          __builtin_amdgcn_s_sleep(1);
          p0 = pkt_load_l2(&g_pktA[rp][b0 + bq + 0][2 * up]);
          p1 = pkt_load_l2(&g_pktA[rp][b0 + bq + 1][2 * up]);
          p2 = pkt_load_l2(&g_pktA[rp][b0 + bq + 2][2 * up]);
          p3 = pkt_load_l2(&g_pktA[rp][b0 + bq + 3][2 * up]);
          PKT_WAIT4(p0, p1, p2, p3);
          ok = TAGS_OK();
          ++rounds;
        }
        if (!ok) use_local = false; // cross-XCD placement: downgrade for good
      }
      while (!ok) {
        p0 = pkt_load_ic(&g_pktB[rp][b0 + bq + 0][2 * up]);
        p1 = pkt_load_ic(&g_pktB[rp][b0 + bq + 1][2 * up]);
        p2 = pkt_load_ic(&g_pktB[rp][b0 + bq + 2][2 * up]);
        p3 = pkt_load_ic(&g_pktB[rp][b0 + bq + 3][2 * up]);
        PKT_WAIT4(p0, p1, p2, p3);
        ok = TAGS_OK();
        if (!ok) __builtin_amdgcn_s_sleep(1);
      }
      *(float2*)&hx[cur][bq + 0][ho] =
          make_float2(__uint_as_float(p0[0]), __uint_as_float(p0[2]));
      *(float2*)&hx[cur][bq + 1][ho] =
          make_float2(__uint_as_float(p1[0]), __uint_as_float(p1[2]));
      *(float2*)&hx[cur][bq + 2][ho] =
          make_float2(__uint_as_float(p2[0]), __uint_as_float(p2[2]));
      *(float2*)&hx[cur][bq + 3][ho] =
          make_float2(__uint_as_float(p3[0]), __uint_as_float(p3[2]));
    } else {
#pragma unroll
      for (int jj = 0; jj < 4; ++jj)
        *(float2*)&hx[cur][bq + jj][ho] = make_float2(0.f, 0.f);
    }
    __syncthreads(); // A: h staged

    // ---- h-part GEMM (i=0..3) ----
#pragma unroll
    for (int i = 0; i < 4; ++i) {
      const int hoff = pidx(ksl * 4 + i * 64);
      float4 hv[4];
#pragma unroll
      for (int r = 0; r < 4; ++r)
        hv[r] = *(const float4*)&hx[cur][bh * 4 + r][hoff];
#pragma unroll
      for (int j = 0; j < 4; ++j)
#pragma unroll
        for (int r = 0; r < 4; ++r) {
          const float hval = (j == 0) ? hv[r].x : (j == 1) ? hv[r].y
                             : (j == 2) ? hv[r].z : hv[r].w;
#pragma unroll
          for (int cc = 0; cc < 4; ++cc)
            acc[r][cc] += hval * w[(i * 4 + j) * 4 + cc];
        }
    }

    // ---- k-reduce via DPP row_ror (VALU pipe; ksl groups == DPP rows) ----
#pragma unroll
    for (int r = 0; r < 4; ++r)
#pragma unroll
      for (int cc = 0; cc < 4; ++cc)
        acc[r][cc] = rowsum16(acc[r][cc]);
    if (ksl == 0) {
#pragma unroll
      for (int r = 0; r < 4; ++r)
        *(float4*)&zs[bh * 4 + r][cq * 4] =
            make_float4(acc[r][0], acc[r][1], acc[r][2], acc[r][3]);
    }
    __syncthreads(); // B: zs ready

    // ---- gates: tid<64 owns (batch gb, unit u0+gu) ----
    if (tid < 64) {
      const float zi = zs[gb][gu]      + bias_s[gu];
      const float zf = zs[gb][8 + gu]  + bias_s[8 + gu];
      const float zg = zs[gb][16 + gu] + bias_s[16 + gu];
      const float zo = zs[gb][24 + gu] + bias_s[24 + gu];
      const float gi = 1.f / (1.f + __expf(-zi));
      const float gf = 1.f / (1.f + __expf(-zf));
      const float gg = 1.f - 2.f / (1.f + __expf(2.f * zg)); // tanh
      const float go = 1.f / (1.f + __expf(-zo));
      const float cn = gf * creg + gi * gg;
      const float th = 1.f - 2.f / (1.f + __expf(2.f * cn));
      const float hn = go * th;
      const bool msk = (tk_g != 0);
      const float hold = hx[cur][gb][pidx(u0 + gu)];
      const float h2 = msk ? hn : hold;
      creg = msk ? cn : creg;
      const unsigned long long pkt =
          ((unsigned long long)(unsigned)(it + 1) << 32) | __float_as_uint(h2);
      // dual publish: XCD-local L2 copy + device-coherent IC mirror
      __hip_atomic_store(&g_pktA[cur][b0 + gb][u0 + gu], pkt, __ATOMIC_RELAXED,
                         __HIP_MEMORY_SCOPE_WORKGROUP);
      __hip_atomic_store(&g_pktB[cur][b0 + gb][u0 + gu], pkt, __ATOMIC_RELAXED,
                         __HIP_MEMORY_SCOPE_AGENT);
      __builtin_nontemporal_store(
          h2, &out[((size_t)(b0 + gb) * TLEN + it) * DDIM + u0 + gu]);
    }
    xv = xv_n;
    tk_g = tk_g_n;
    // no end barrier: staging of step it+1 writes hx[1-cur]; zs next written
    // only after barrier A(it+1); h ordering is packet-self-clocked.
  }
}

// y = relu(H @ Wd + bd), in place over d_out (h history -> y). 32 rows/block.
__global__ __launch_bounds__(256, 2) void we_proj(
    const float* __restrict__ Wd, const float* __restrict__ bd,
    float* __restrict__ out)
{
  __shared__ float hs[32][260];
  __shared__ float ws[32][260];
  __shared__ float bds[DDIM];

  const int tid = threadIdx.x;
  const size_t row0 = (size_t)blockIdx.x * 32;

#pragma unroll
  for (int j2 = 0; j2 < 8; ++j2) {
    const int idx = tid + j2 * 256;
    const int r = idx >> 6;
    const int cq = idx & 63;
    *(float4*)&hs[r][cq * 4] = *(const float4*)&out[(row0 + r) * DDIM + cq * 4];
  }
  bds[tid] = bd[tid];

  const int rg = tid >> 5;
  const int c0 = (tid & 31) * 8;
  float acc[4][8];
#pragma unroll
  for (int i = 0; i < 4; ++i)
#pragma unroll
    for (int c = 0; c < 8; ++c) acc[i][c] = 0.f;

  for (int kt = 0; kt < 8; ++kt) {
    __syncthreads();
#pragma unroll
    for (int j2 = 0; j2 < 8; ++j2) {
      const int idx = tid + j2 * 256;
      const int kk = idx >> 6;
      const int cq = idx & 63;
      *(float4*)&ws[kk][cq * 4] =
          *(const float4*)&Wd[(size_t)(kt * 32 + kk) * DDIM + cq * 4];
    }
    __syncthreads();
#pragma unroll
    for (int kk = 0; kk < 32; ++kk) {
      const float4 wv0 = *(const float4*)&ws[kk][c0];
      const float4 wv1 = *(const float4*)&ws[kk][c0 + 4];
#pragma unroll
      for (int i = 0; i < 4; ++i) {
        const float hval = hs[rg + i * 8][kt * 32 + kk];
        acc[i][0] += hval * wv0.x; acc[i][1] += hval * wv0.y;
        acc[i][2] += hval * wv0.z; acc[i][3] += hval * wv0.w;
        acc[i][4] += hval * wv1.x; acc[i][5] += hval * wv1.y;
        acc[i][6] += hval * wv1.z; acc[i][7] += hval * wv1.w;
      }
    }
  }
#pragma unroll
  for (int i = 0; i < 4; ++i) {
    float4 y0, y1;
    y0.x = fmaxf(acc[i][0] + bds[c0 + 0], 0.f);
    y0.y = fmaxf(acc[i][1] + bds[c0 + 1], 0.f);
    y0.z = fmaxf(acc[i][2] + bds[c0 + 2], 0.f);
    y0.w = fmaxf(acc[i][3] + bds[c0 + 3], 0.f);
    y1.x = fmaxf(acc[i][4] + bds[c0 + 4], 0.f);
    y1.y = fmaxf(acc[i][5] + bds[c0 + 5], 0.f);
    y1.z = fmaxf(acc[i][6] + bds[c0 + 6], 0.f);
    y1.w = fmaxf(acc[i][7] + bds[c0 + 7], 0.f);
    const size_t orow = (row0 + rg + i * 8) * DDIM;
    *(float4*)&out[orow + c0]     = y0;
    *(float4*)&out[orow + c0 + 4] = y1;
  }
}

extern "C" void kernel_launch(void* const* d_in, const int* in_sizes, int n_in,
                              void* d_out, int out_size, void* d_ws, size_t ws_size,
                              hipStream_t stream) {
  const int*   tokens = (const int*)d_in[0];
  const float* emb    = (const float*)d_in[1];
  const float* Wk     = (const float*)d_in[2];
  const float* Wr     = (const float*)d_in[3];
  const float* bz     = (const float*)d_in[4];
  const float* Wd     = (const float*)d_in[5];
  const float* bd     = (const float*)d_in[6];
  float* out = (float*)d_out;
  (void)in_sizes; (void)n_in; (void)out_size; (void)d_ws; (void)ws_size;
  hipLaunchKernelGGL(we_lstm, dim3(512), dim3(256), 0, stream,
                     tokens, emb, Wk, Wr, bz, out);
  hipLaunchKernelGGL(we_proj, dim3(128 * TLEN / 32), dim3(256), 0, stream,
                     Wd, bd, out);
}

// Round 11
// 3650.018 us; speedup vs baseline: 2.2433x; 1.0125x over previous
//
#include <hip/hip_runtime.h>
#include <cstddef>

// WordEncoder: emb gather -> masked LSTM (T=1024) -> relu(h@Wd+bd)
// R11 = R8 (self-validating (tag|h) packets, dual-published: workgroup->L2 +
// agent->IC; proven correct) + a cheap SOUND certificate: one agent-scope IC
// counter per batch-group. Producers bump it after vmcnt(0) on their packet
// stores; consumers spin on that single dword (1 coalesced 4B load per wave
// -- kills R8's packet-poll storm) and only then reload packets once. Tags
// still validate every h value consumed; tag mismatch after a passed
// certificate implies cross-XCD placement -> sticky downgrade to IC mirror.
// 512 blocks = 16 batch-groups x 32 unit-groups, 2 blocks/CU.

typedef unsigned int u32x4 __attribute__((ext_vector_type(4)));

constexpr int TLEN = 1024;
constexpr int EDIM = 128;
constexpr int UDIM = 256;
constexpr int DDIM = 256;

constexpr int NBG  = 16;   // batch groups (32 producer blocks each)
constexpr int BPB  = 8;    // batches per block
constexpr int UPB  = 8;    // units per block
constexpr int ZCOL = 32;   // z cols per block (4 gates x 8 units)
constexpr int HXROW = 432; // (384/32)*36 padded row
constexpr int ZROW = 36;   // 32 + 4 pad

__device__ unsigned long long g_pktA[2][128][256]; // XCD-local path (L2)
__device__ unsigned long long g_pktB[2][128][256]; // device-coherent mirror (IC)
__device__ unsigned           g_cnt[NBG][32];      // agent-scope certificates

__device__ __forceinline__ int pidx(int k) { return ((k >> 5) * 36) + (k & 31); }

__device__ __forceinline__ u32x4 pkt_load_ic(const unsigned long long* p) {
  u32x4 v;
  asm volatile("global_load_dwordx4 %0, %1, off sc0 sc1" : "=v"(v) : "v"(p));
  return v;
}
__device__ __forceinline__ u32x4 pkt_load_l2(const unsigned long long* p) {
  u32x4 v; // sc0: bypass L1, hit the XCD-coherent L2
  asm volatile("global_load_dwordx4 %0, %1, off sc0" : "=v"(v) : "v"(p));
  return v;
}
__device__ __forceinline__ unsigned cnt_load_ic(const unsigned* p) {
  unsigned v;
  asm volatile("global_load_dword %0, %1, off sc0 sc1" : "=v"(v) : "v"(p));
  asm volatile("s_waitcnt vmcnt(0)" : "+v"(v) :: "memory");
  return v;
}
#define PKT_WAIT4(a, b, c, d) \
  asm volatile("s_waitcnt vmcnt(0)" : "+v"(a), "+v"(b), "+v"(c), "+v"(d) :: "memory")
#define TAGS_OK() \
  ((p0[1] == want) & (p0[3] == want) & (p1[1] == want) & (p1[3] == want) & \
   (p2[1] == want) & (p2[3] == want) & (p3[1] == want) & (p3[3] == want))

// Sum across the 16-lane DPP row (ksl groups == DPP rows). Pure VALU pipe.
__device__ __forceinline__ float rowsum16(float v) {
  v += __int_as_float(
      __builtin_amdgcn_mov_dpp(__float_as_int(v), 0x121, 0xf, 0xf, true));
  v += __int_as_float(
      __builtin_amdgcn_mov_dpp(__float_as_int(v), 0x122, 0xf, 0xf, true));
  v += __int_as_float(
      __builtin_amdgcn_mov_dpp(__float_as_int(v), 0x124, 0xf, 0xf, true));
  v += __int_as_float(
      __builtin_amdgcn_mov_dpp(__float_as_int(v), 0x128, 0xf, 0xf, true));
  return v;
}

__global__ void we_init() {
  const int i = blockIdx.x * 256 + threadIdx.x;
  if (i < NBG * 32)
    __hip_atomic_store(&(&g_cnt[0][0])[i], 0u, __ATOMIC_RELAXED,
                       __HIP_MEMORY_SCOPE_AGENT);
}

__global__ __launch_bounds__(256, 2) void we_lstm(
    const int* __restrict__ tokens, const float* __restrict__ emb,
    const float* __restrict__ Wk, const float* __restrict__ Wr,
    const float* __restrict__ bz, float* __restrict__ out)
{
  __shared__ float hx[2][BPB][HXROW]; // parity-dbuf [h(256)|x(128)], padded
  __shared__ float zs[BPB][ZROW];     // reduced z (pre-bias)
  __shared__ float bias_s[ZCOL];

  const int tid = threadIdx.x;
  const int bid = blockIdx.x;
  // Group remap: a bg's 32 blocks share bid%8 (one XCD under round-robin);
  // co-resident pair (bid, bid+256) -> same CU, different bg.
  const int bg  = ((bid & 7) << 1) | ((bid >> 8) & 1);
  const int ug  = (bid >> 3) & 31;
  const int b0  = bg * BPB;
  const int u0  = ug * UPB;

  // GEMM decomposition: 256 = 2 row-halves x 8 col-quads x 16 k-slices;
  // 4 batch rows per thread. k = ksl*4 + i*64 + j ; i<4 h-part, i>=4 x-part.
  const int ksl = tid & 15;
  const int cq  = (tid >> 4) & 7;
  const int bh  = tid >> 7;

  // ---- prologue: weight slice into registers (24k x 4c per thread) ----
  float w[96];
#pragma unroll
  for (int i = 0; i < 6; ++i)
#pragma unroll
    for (int j = 0; j < 4; ++j) {
      const int k = ksl * 4 + i * 64 + j;
#pragma unroll
      for (int cc = 0; cc < 4; ++cc) {
        const int c   = cq * 4 + cc;
        const int col = ((c >> 3) << 8) + u0 + (c & 7);
        w[(i * 4 + j) * 4 + cc] =
            (k < UDIM) ? Wr[k * 1024 + col] : Wk[(k - UDIM) * 1024 + col];
      }
    }
  if (tid < ZCOL) bias_s[tid] = bz[((tid >> 3) << 8) + u0 + (tid & 7)];

  float creg = 0.f;
  const int gb = tid >> 3, gu = tid & 7;         // gates (tid<64)
  const int xb = tid >> 5, xe = (tid & 31) << 2; // x stage
  const int up = tid & 127, bq = (tid >> 7) * 4; // pkt stage

  bool use_local = true; // self-tuning exchange path (sticky downgrade)

  // ---- prefetch step 0 x and gate-token ----
  float4 xv = *(const float4*)&emb[(size_t)tokens[(b0 + xb) * TLEN] * EDIM + xe];
  int tk_g = (tid < 64) ? tokens[(b0 + gb) * TLEN] : 1;

  for (int it = 0; it < TLEN; ++it) {
    const int cur = it & 1;

    // ---- write prefetched x -> LDS ----
    *(float4*)&hx[cur][xb][pidx(UDIM + xe)] = xv;
    __syncthreads(); // X: x staged

    float acc[4][4];
#pragma unroll
    for (int r = 0; r < 4; ++r) {
      acc[r][0] = 0.f; acc[r][1] = 0.f; acc[r][2] = 0.f; acc[r][3] = 0.f;
    }
    // ---- x-part GEMM (i=4,5) ----
#pragma unroll
    for (int i = 4; i < 6; ++i) {
      const int hoff = pidx(ksl * 4 + i * 64);
      float4 hv[4];
#pragma unroll
      for (int r = 0; r < 4; ++r)
        hv[r] = *(const float4*)&hx[cur][bh * 4 + r][hoff];
#pragma unroll
      for (int j = 0; j < 4; ++j)
#pragma unroll
        for (int r = 0; r < 4; ++r) {
          const float hval = (j == 0) ? hv[r].x : (j == 1) ? hv[r].y
                             : (j == 2) ? hv[r].z : hv[r].w;
#pragma unroll
          for (int cc = 0; cc < 4; ++cc)
            acc[r][cc] += hval * w[(i * 4 + j) * 4 + cc];
        }
    }

    // ---- optimistic early packet load (R8 fast path) ----
    u32x4 p0, p1, p2, p3;
    const unsigned want = (unsigned)it; // producer tag = step+1
    const int rp = (it + 1) & 1;        // == (it-1)&1
    if (it > 0) {
      if (use_local) {
        p0 = pkt_load_l2(&g_pktA[rp][b0 + bq + 0][2 * up]);
        p1 = pkt_load_l2(&g_pktA[rp][b0 + bq + 1][2 * up]);
        p2 = pkt_load_l2(&g_pktA[rp][b0 + bq + 2][2 * up]);
        p3 = pkt_load_l2(&g_pktA[rp][b0 + bq + 3][2 * up]);
      } else {
        p0 = pkt_load_ic(&g_pktB[rp][b0 + bq + 0][2 * up]);
        p1 = pkt_load_ic(&g_pktB[rp][b0 + bq + 1][2 * up]);
        p2 = pkt_load_ic(&g_pktB[rp][b0 + bq + 2][2 * up]);
        p3 = pkt_load_ic(&g_pktB[rp][b0 + bq + 3][2 * up]);
      }
    }

    // ---- prefetch next-step x / gate-token (completes under the wait) ----
    float4 xv_n;
    int tk_g_n = 1;
    if (it + 1 < TLEN) {
      const int tk_x = tokens[(b0 + xb) * TLEN + it + 1];
      xv_n = *(const float4*)&emb[(size_t)tk_x * EDIM + xe];
      if (tid < 64) tk_g_n = tokens[(b0 + gb) * TLEN + it + 1];
    }

    // ---- resolve: tags -> certificate spin -> reload -> sticky IC loop ----
    const int ho = pidx(2 * up);
    if (it > 0) {
      PKT_WAIT4(p0, p1, p2, p3);
      bool ok = TAGS_OK();
      if (!ok) {
        // cheap certificate: all 32 producers of bg published step it-1
        const unsigned wantc = 32u * (unsigned)it;
        while (cnt_load_ic(&g_cnt[bg][0]) < wantc)
          __builtin_amdgcn_s_sleep(1);
        if (use_local) { // certified: same-XCD pktA must now be fresh
          p0 = pkt_load_l2(&g_pktA[rp][b0 + bq + 0][2 * up]);
          p1 = pkt_load_l2(&g_pktA[rp][b0 + bq + 1][2 * up]);
          p2 = pkt_load_l2(&g_pktA[rp][b0 + bq + 2][2 * up]);
          p3 = pkt_load_l2(&g_pktA[rp][b0 + bq + 3][2 * up]);
          PKT_WAIT4(p0, p1, p2, p3);
          ok = TAGS_OK();
          if (!ok) use_local = false; // cross-XCD placement: downgrade
        }
        while (!ok) { // IC mirror always fresh post-certificate
          p0 = pkt_load_ic(&g_pktB[rp][b0 + bq + 0][2 * up]);
          p1 = pkt_load_ic(&g_pktB[rp][b0 + bq + 1][2 * up]);
          p2 = pkt_load_ic(&g_pktB[rp][b0 + bq + 2][2 * up]);
          p3 = pkt_load_ic(&g_pktB[rp][b0 + bq + 3][2 * up]);
          PKT_WAIT4(p0, p1, p2, p3);
          ok = TAGS_OK();
          if (!ok) __builtin_amdgcn_s_sleep(1);
        }
      }
      *(float2*)&hx[cur][bq + 0][ho] =
          make_float2(__uint_as_float(p0[0]), __uint_as_float(p0[2]));
      *(float2*)&hx[cur][bq + 1][ho] =
          make_float2(__uint_as_float(p1[0]), __uint_as_float(p1[2]));
      *(float2*)&hx[cur][bq + 2][ho] =
          make_float2(__uint_as_float(p2[0]), __uint_as_float(p2[2]));
      *(float2*)&hx[cur][bq + 3][ho] =
          make_float2(__uint_as_float(p3[0]), __uint_as_float(p3[2]));
    } else {
#pragma unroll
      for (int jj = 0; jj < 4; ++jj)
        *(float2*)&hx[cur][bq + jj][ho] = make_float2(0.f, 0.f);
    }
    __syncthreads(); // A: h staged

    // ---- h-part GEMM (i=0..3) ----
#pragma unroll
    for (int i = 0; i < 4; ++i) {
      const int hoff = pidx(ksl * 4 + i * 64);
      float4 hv[4];
#pragma unroll
      for (int r = 0; r < 4; ++r)
        hv[r] = *(const float4*)&hx[cur][bh * 4 + r][hoff];
#pragma unroll
      for (int j = 0; j < 4; ++j)
#pragma unroll
        for (int r = 0; r < 4; ++r) {
          const float hval = (j == 0) ? hv[r].x : (j == 1) ? hv[r].y
                             : (j == 2) ? hv[r].z : hv[r].w;
#pragma unroll
          for (int cc = 0; cc < 4; ++cc)
            acc[r][cc] += hval * w[(i * 4 + j) * 4 + cc];
        }
    }

    // ---- k-reduce via DPP row_ror (VALU pipe; ksl groups == DPP rows) ----
#pragma unroll
    for (int r = 0; r < 4; ++r)
#pragma unroll
      for (int cc = 0; cc < 4; ++cc)
        acc[r][cc] = rowsum16(acc[r][cc]);
    if (ksl == 0) {
#pragma unroll
      for (int r = 0; r < 4; ++r)
        *(float4*)&zs[bh * 4 + r][cq * 4] =
            make_float4(acc[r][0], acc[r][1], acc[r][2], acc[r][3]);
    }
    __syncthreads(); // B: zs ready

    // ---- gates + publish + certificate bump (wave 0) ----
    if (tid < 64) {
      const float zi = zs[gb][gu]      + bias_s[gu];
      const float zf = zs[gb][8 + gu]  + bias_s[8 + gu];
      const float zg = zs[gb][16 + gu] + bias_s[16 + gu];
      const float zo = zs[gb][24 + gu] + bias_s[24 + gu];
      const float gi = 1.f / (1.f + __expf(-zi));
      const float gf = 1.f / (1.f + __expf(-zf));
      const float gg = 1.f - 2.f / (1.f + __expf(2.f * zg)); // tanh
      const float go = 1.f / (1.f + __expf(-zo));
      const float cn = gf * creg + gi * gg;
      const float th = 1.f - 2.f / (1.f + __expf(2.f * cn));
      const float hn = go * th;
      const bool msk = (tk_g != 0);
      const float hold = hx[cur][gb][pidx(u0 + gu)];
      const float h2 = msk ? hn : hold;
      creg = msk ? cn : creg;
      const unsigned long long pkt =
          ((unsigned long long)(unsigned)(it + 1) << 32) | __float_as_uint(h2);
      // dual publish: XCD-local L2 copy + device-coherent IC mirror
      __hip_atomic_store(&g_pktA[cur][b0 + gb][u0 + gu], pkt, __ATOMIC_RELAXED,
                         __HIP_MEMORY_SCOPE_WORKGROUP);
      __hip_atomic_store(&g_pktB[cur][b0 + gb][u0 + gu], pkt, __ATOMIC_RELAXED,
                         __HIP_MEMORY_SCOPE_AGENT);
      __builtin_nontemporal_store(
          h2, &out[((size_t)(b0 + gb) * TLEN + it) * DDIM + u0 + gu]);
      // certificate: stores acked, then one agent-scope bump per block
      asm volatile("s_waitcnt vmcnt(0)" ::: "memory");
      if (tid == 0)
        __hip_atomic_fetch_add(&g_cnt[bg][0], 1u, __ATOMIC_RELAXED,
                               __HIP_MEMORY_SCOPE_AGENT);
    }
    xv = xv_n;
    tk_g = tk_g_n;
    // no end barrier: step it+1 writes hx[1-cur]; zs rewritten only after
    // barrier A(it+1); cross-block ordering is tag+certificate-clocked.
  }
}

// y = relu(H @ Wd + bd), in place over d_out (h history -> y). 32 rows/block.
__global__ __launch_bounds__(256, 2) void we_proj(
    const float* __restrict__ Wd, const float* __restrict__ bd,
    float* __restrict__ out)
{
  __shared__ float hs[32][260];
  __shared__ float ws[32][260];
  __shared__ float bds[DDIM];

  const int tid = threadIdx.x;
  const size_t row0 = (size_t)blockIdx.x * 32;

#pragma unroll
  for (int j2 = 0; j2 < 8; ++j2) {
    const int idx = tid + j2 * 256;
    const int r = idx >> 6;
    const int cq = idx & 63;
    *(float4*)&hs[r][cq * 4] = *(const float4*)&out[(row0 + r) * DDIM + cq * 4];
  }
  bds[tid] = bd[tid];

  const int rg = tid >> 5;
  const int c0 = (tid & 31) * 8;
  float acc[4][8];
#pragma unroll
  for (int i = 0; i < 4; ++i)
#pragma unroll
    for (int c = 0; c < 8; ++c) acc[i][c] = 0.f;

  for (int kt = 0; kt < 8; ++kt) {
    __syncthreads();
#pragma unroll
    for (int j2 = 0; j2 < 8; ++j2) {
      const int idx = tid + j2 * 256;
      const int kk = idx >> 6;
      const int cq = idx & 63;
      *(float4*)&ws[kk][cq * 4] =
          *(const float4*)&Wd[(size_t)(kt * 32 + kk) * DDIM + cq * 4];
    }
    __syncthreads();
#pragma unroll
    for (int kk = 0; kk < 32; ++kk) {
      const float4 wv0 = *(const float4*)&ws[kk][c0];
      const float4 wv1 = *(const float4*)&ws[kk][c0 + 4];
#pragma unroll
      for (int i = 0; i < 4; ++i) {
        const float hval = hs[rg + i * 8][kt * 32 + kk];
        acc[i][0] += hval * wv0.x; acc[i][1] += hval * wv0.y;
        acc[i][2] += hval * wv0.z; acc[i][3] += hval * wv0.w;
        acc[i][4] += hval * wv1.x; acc[i][5] += hval * wv1.y;
        acc[i][6] += hval * wv1.z; acc[i][7] += hval * wv1.w;
      }
    }
  }
#pragma unroll
  for (int i = 0; i < 4; ++i) {
    float4 y0, y1;
    y0.x = fmaxf(acc[i][0] + bds[c0 + 0], 0.f);
    y0.y = fmaxf(acc[i][1] + bds[c0 + 1], 0.f);
    y0.z = fmaxf(acc[i][2] + bds[c0 + 2], 0.f);
    y0.w = fmaxf(acc[i][3] + bds[c0 + 3], 0.f);
    y1.x = fmaxf(acc[i][4] + bds[c0 + 4], 0.f);
    y1.y = fmaxf(acc[i][5] + bds[c0 + 5], 0.f);
    y1.z = fmaxf(acc[i][6] + bds[c0 + 6], 0.f);
    y1.w = fmaxf(acc[i][7] + bds[c0 + 7], 0.f);
    const size_t orow = (row0 + rg + i * 8) * DDIM;
    *(float4*)&out[orow + c0]     = y0;
    *(float4*)&out[orow + c0 + 4] = y1;
  }
}

extern "C" void kernel_launch(void* const* d_in, const int* in_sizes, int n_in,
                              void* d_out, int out_size, void* d_ws, size_t ws_size,
                              hipStream_t stream) {
  const int*   tokens = (const int*)d_in[0];
  const float* emb    = (const float*)d_in[1];
  const float* Wk     = (const float*)d_in[2];
  const float* Wr     = (const float*)d_in[3];
  const float* bz     = (const float*)d_in[4];
  const float* Wd     = (const float*)d_in[5];
  const float* bd     = (const float*)d_in[6];
  float* out = (float*)d_out;
  (void)in_sizes; (void)n_in; (void)out_size; (void)d_ws; (void)ws_size;
  hipLaunchKernelGGL(we_init, dim3(2), dim3(256), 0, stream);
  hipLaunchKernelGGL(we_lstm, dim3(512), dim3(256), 0, stream,
                     tokens, emb, Wk, Wr, bz, out);
  hipLaunchKernelGGL(we_proj, dim3(128 * TLEN / 32), dim3(256), 0, stream,
                     Wd, bd, out);
}